// Round 7
// baseline (436.950 us; speedup 1.0000x reference)
//
#include <hip/hip_runtime.h>
#include <hip/hip_bf16.h>

typedef __bf16 bf16;
typedef __bf16 bf16x8 __attribute__((ext_vector_type(8)));
typedef __bf16 bf16x4 __attribute__((ext_vector_type(4)));
typedef float f32x4 __attribute__((ext_vector_type(4)));
typedef unsigned int u32;

#define NPIX 16384
#define CDIM 192

// Tiled-swizzled operand layout ("panel" layout), shared by xt, qkv_wb, proj_wb,
// gated_t:  element (row, k) of a [R][192] matrix lives at
//   panel(kc = k>>5) * R*32  +  (row>>4)*512  +  (slot)*8 + (k&7)
//   slot = j8*16 + ((row&15) ^ (j8<<1)),  j8 = (k>>3)&3
// A lane's MFMA fragment (row group g, k-chunk kc) is the contiguous 16B at
//   panel + g*512 + slot8   with slot8 = ((qd<<4) + (c0^(qd<<1)))<<3
// -> 64 lanes cover a contiguous 1KB: direct global->VGPR fragment loads are
// fully coalesced (8 full 128B lines). No LDS needed in the GEMM at all.

// ------------------------------------------------- input dtype detector
__global__ __launch_bounds__(256) void detect_kernel(
    const u32* __restrict__ xw, int* __restrict__ flag) {
  int tid = threadIdx.x;
  int cnt = 0;
  for (int i = 0; i < 32; i++) {
    u32 w = xw[tid * 32 + i];
    u32 e = (w >> 7) & 0xFFu;   // exponent of low-half bf16
    if (e >= 0xC0u) cnt++;
  }
  for (int off = 32; off; off >>= 1) cnt += __shfl_down(cnt, off);
  __shared__ int red[4];
  if ((tid & 63) == 0) red[tid >> 6] = cnt;
  __syncthreads();
  if (tid == 0) *flag = (red[0] + red[1] + red[2] + red[3] >= 16) ? 1 : 0;
}

// ------------------------------------------------- weights -> bf16 (merged)
// qkv_w (M=576) and proj_w (M=192) are stored in panel layout; dw_w linear.
__global__ __launch_bounds__(256) void wconvert_kernel(
    const void* __restrict__ s0, bf16* __restrict__ d0,
    const void* __restrict__ s1, bf16* __restrict__ d1,
    const void* __restrict__ s2, bf16* __restrict__ d2,
    const int* __restrict__ flag) {
  int which = blockIdx.y;
  const void* src = which == 0 ? s0 : (which == 1 ? s1 : s2);
  bf16* dst = which == 0 ? d0 : (which == 1 ? d1 : d2);
  int n = which == 0 ? 110592 : (which == 1 ? 5184 : 36864);
  int base = (blockIdx.x * 256 + threadIdx.x) * 8;
  if (base >= n) return;
  bf16x8 o;
  if (*flag) {
    const float* s = (const float*)src;
    float4 lo = *(const float4*)(s + base);
    float4 hi = *(const float4*)(s + base + 4);
    o[0] = (bf16)lo.x; o[1] = (bf16)lo.y; o[2] = (bf16)lo.z; o[3] = (bf16)lo.w;
    o[4] = (bf16)hi.x; o[5] = (bf16)hi.y; o[6] = (bf16)hi.z; o[7] = (bf16)hi.w;
  } else {
    o = *(const bf16x8*)((const bf16*)src + base);
  }
  if (which != 1) {
    int M = (which == 0) ? 576 : 192;
    int m = base / 192, k = base - m * 192;          // k % 8 == 0
    int kc = k >> 5, j8 = (k >> 3) & 3;
    size_t dstoff = (size_t)kc * M * 32 + ((size_t)(m >> 4) << 9)
                  + (((j8 << 4) + ((m & 15) ^ (j8 << 1))) << 3);
    *(bf16x8*)(dst + dstoff) = o;
  } else {
    *(bf16x8*)(dst + base) = o;
  }
}

// ------------------------------------------------- x -> xt panels (+ fused router)
// Thread loads 8 c-rows x 4 n (coalesced); writes 4x 16B chunks in panel layout.
// Router fused: same x values dotted against W^T (LDS, broadcast reads) in f32,
// reduced shfl_xor(32) intra-wave then 4-way via LDS; identical top-2 gate math.
__global__ __launch_bounds__(256) void transpose_kernel(
    const void* __restrict__ xraw, bf16* __restrict__ xt,
    const int* __restrict__ flag, const void* __restrict__ wmain,
    const void* __restrict__ waux, const int* __restrict__ task,
    float* __restrict__ gates2) {
  __shared__ float wT[CDIM][8];      // 6 KB
  __shared__ float lred[4][128][8];  // 16 KB
  int t = threadIdx.x;
  int b = blockIdx.y;
  int n0 = blockIdx.x * 128;
  int f = *flag;
  const void* rw = (*task == 0) ? wmain : waux;
  for (int i = t; i < 8 * CDIM; i += 256) {
    int h = i / CDIM, c = i - h * CDIM;
    wT[c][h] = f ? ((const float*)rw)[i] : (float)((const bf16*)rw)[i];
  }
  __syncthreads();
  int nl = (t & 31) * 4;
  int cb = (t >> 5) * 8;             // 0..56
  float l[4][8];
#pragma unroll
  for (int j = 0; j < 4; j++)
#pragma unroll
    for (int h = 0; h < 8; h++) l[j][h] = 0.f;
  for (int ch = 0; ch < 3; ch++) {
    int c8 = ch * 64 + cb;
    float v[8][4];
    if (f) {
      const float* xp = (const float*)xraw + ((size_t)b * CDIM << 14) + n0 + nl;
#pragma unroll
      for (int i = 0; i < 8; i++) {
        float4 q = *(const float4*)(xp + ((size_t)(c8 + i) << 14));
        v[i][0] = q.x; v[i][1] = q.y; v[i][2] = q.z; v[i][3] = q.w;
      }
    } else {
      const bf16* xp = (const bf16*)xraw + ((size_t)b * CDIM << 14) + n0 + nl;
#pragma unroll
      for (int i = 0; i < 8; i++) {
        bf16x4 q = *(const bf16x4*)(xp + ((size_t)(c8 + i) << 14));
#pragma unroll
        for (int j = 0; j < 4; j++) v[i][j] = (float)q[j];
      }
    }
    // router partials
#pragma unroll
    for (int i = 0; i < 8; i++) {
      float4 wlo = *(const float4*)&wT[c8 + i][0];
      float4 whi = *(const float4*)&wT[c8 + i][4];
#pragma unroll
      for (int j = 0; j < 4; j++) {
        float xv = v[i][j];
        l[j][0] += xv * wlo.x; l[j][1] += xv * wlo.y;
        l[j][2] += xv * wlo.z; l[j][3] += xv * wlo.w;
        l[j][4] += xv * whi.x; l[j][5] += xv * whi.y;
        l[j][6] += xv * whi.z; l[j][7] += xv * whi.w;
      }
    }
    int kc = c8 >> 5, j8 = (c8 >> 3) & 3;
    size_t pb = (((size_t)b * 6 + kc) << 19);
#pragma unroll
    for (int j = 0; j < 4; j++) {
      bf16x8 o;
#pragma unroll
      for (int i = 0; i < 8; i++) o[i] = (bf16)v[i][j];
      int nn = n0 + nl + j;
      size_t dst = pb + ((size_t)(nn >> 4) << 9)
                 + (((j8 << 4) + ((nn & 15) ^ (j8 << 1))) << 3);
      *(bf16x8*)(xt + dst) = o;
    }
  }
  // ---- router reduce: g-bit0 is tid bit5 (intra-wave) -> shfl_xor 32
#pragma unroll
  for (int j = 0; j < 4; j++)
#pragma unroll
    for (int h = 0; h < 8; h++) l[j][h] += __shfl_xor(l[j][h], 32);
  int lane = t & 63, wid = t >> 6;
  if (lane < 32) {
#pragma unroll
    for (int j = 0; j < 4; j++) {
      *(float4*)&lred[wid][nl + j][0] = make_float4(l[j][0], l[j][1], l[j][2], l[j][3]);
      *(float4*)&lred[wid][nl + j][4] = make_float4(l[j][4], l[j][5], l[j][6], l[j][7]);
    }
  }
  __syncthreads();
  if (t < 128) {
    float lg[8];
#pragma unroll
    for (int h = 0; h < 8; h++)
      lg[h] = (lred[0][t][h] + lred[1][t][h]) + (lred[2][t][h] + lred[3][t][h]);
    int i1 = 0;
#pragma unroll
    for (int h = 1; h < 8; h++) if (lg[h] > lg[i1]) i1 = h;
    int i2 = (i1 == 0) ? 1 : 0;
#pragma unroll
    for (int h = 0; h < 8; h++) if (h != i1 && lg[h] > lg[i2]) i2 = h;
    float e = __expf(lg[i2] - lg[i1]);
    float g1 = 2.f / (1.f + e);
    float g2 = e * g1;
    float* gb = gates2 + (((size_t)b * 8) << 14) + n0 + t;
#pragma unroll
    for (int h = 0; h < 8; h++)
      gb[(size_t)h << 14] = (h == i1) ? g1 : ((h == i2) ? g2 : 0.f);
  }
}

// ------------------------------------------------- GEMM v7: panel-direct, no LDS
// C[z][m][n] = sum_k A[m][k] * Xt[z][n][k].  Block 96m x 256n, wave = 96m x 64n.
// Panel layout makes every fragment a contiguous per-wave 1KB global load ->
// direct global->VGPR, fully coalesced. No LDS, no barriers, no vmcnt drains;
// 10 independent loads per K-step hoist over 24 MFMAs. B is XCD-local L2
// (z = ord%8), A panel is tiny and L2-hot. Swapped-operand epilogue: lane's
// 4 acc values = 4 consecutive n -> 8B bf16x4 / 16B float4 stores.
__global__ __launch_bounds__(256) void wgemm2_kernel(
    const bf16* __restrict__ A, const bf16* __restrict__ Xt,
    void* __restrict__ C, int M, const int* __restrict__ flag, int finalout) {
  int tid = threadIdx.x;
  int wave = tid >> 6, lane = tid & 63;
  int c0 = lane & 15, qd = lane >> 4;

  int nm = M / 96;                                   // 6 (qkv) or 2 (proj)
  int ord = blockIdx.x + nm * (blockIdx.y + (blockIdx.z << 6));
  int z = ord & 7;                                   // one batch per XCD
  int local = ord >> 3;
  int mt = local % nm;                               // m fast within XCD
  int nt = local / nm;
  int m0 = mt * 96, n0 = nt << 8;

  const bf16* Xb = Xt + (size_t)z * CDIM * NPIX;
  size_t cbase = (size_t)z * M * NPIX;
  int Mx32 = M * 32;

  int slot8 = ((qd << 4) + (c0 ^ (qd << 1))) << 3;
  const bf16* Ap = A + (size_t)mt * 6 * 512 + slot8;              // + kc*Mx32 + mi*512
  const bf16* Bp = Xb + ((size_t)((nt << 4) + (wave << 2)) << 9) + slot8; // + kc<<19 + nj*512

  f32x4 acc[6][4];
#pragma unroll
  for (int i = 0; i < 6; i++)
#pragma unroll
    for (int j = 0; j < 4; j++) acc[i][j] = {0.f, 0.f, 0.f, 0.f};

#pragma unroll
  for (int kc = 0; kc < 6; kc++) {
    bf16x8 af[6], bfr[4];
#pragma unroll
    for (int nj = 0; nj < 4; nj++)
      bfr[nj] = *(const bf16x8*)(Bp + ((size_t)kc << 19) + nj * 512);
#pragma unroll
    for (int mi = 0; mi < 6; mi++)
      af[mi] = *(const bf16x8*)(Ap + (size_t)kc * Mx32 + mi * 512);
#pragma unroll
    for (int mi = 0; mi < 6; mi++)
#pragma unroll
      for (int nj = 0; nj < 4; nj++)
        acc[mi][nj] = __builtin_amdgcn_mfma_f32_16x16x32_bf16(bfr[nj], af[mi], acc[mi][nj], 0, 0, 0);
  }

  // epilogue: lane holds C[m = m0+mi*16+c0][n = n_base+nj*16 .. +3]
  int f32o = finalout && (*flag);
  int n_base = n0 + (wave << 6) + (qd << 2);
#pragma unroll
  for (int mi = 0; mi < 6; mi++) {
    size_t rowb = cbase + ((size_t)(m0 + (mi << 4) + c0) << 14) + n_base;
#pragma unroll
    for (int nj = 0; nj < 4; nj++) {
      if (f32o) {
        *(float4*)((float*)C + rowb + (nj << 4)) =
            make_float4(acc[mi][nj][0], acc[mi][nj][1], acc[mi][nj][2], acc[mi][nj][3]);
      } else {
        bf16x4 o;
        o[0] = (bf16)acc[mi][nj][0]; o[1] = (bf16)acc[mi][nj][1];
        o[2] = (bf16)acc[mi][nj][2]; o[3] = (bf16)acc[mi][nj][3];
        *(bf16x4*)((bf16*)C + rowb + (nj << 4)) = o;
      }
    }
  }
}

// ----------------------------------------------- depthwise 3x3 + q/k sumsq
// 8x4 output patch per thread (proven best: round-5): 6 input rows serve 4
// output rows, weights/addressing/reduction amortized 4x, 6 row loads of ILP.
__global__ __launch_bounds__(256) void dwconv_kernel(
    const bf16* __restrict__ qkv, const bf16* __restrict__ w9,
    bf16* __restrict__ out, float* __restrict__ sumsq) {
  int tid = threadIdx.x;
  int ch = blockIdx.y, b = blockIdx.z;
  int xs = (tid & 15) << 3;                      // 0..120
  int y0 = (blockIdx.x << 6) + ((tid >> 4) << 2);  // 4-row group
  const bf16* in = qkv + (((size_t)(b * 576 + ch)) << 14);
  float wv[9];
#pragma unroll
  for (int i = 0; i < 9; i++) wv[i] = (float)w9[ch * 9 + i];
  float o[4][8];
#pragma unroll
  for (int r = 0; r < 4; r++)
#pragma unroll
    for (int i = 0; i < 8; i++) o[r][i] = 0.f;
#pragma unroll
  for (int rr = 0; rr < 6; rr++) {
    int yy = y0 - 1 + rr;
    if (yy < 0 || yy > 127) continue;            // zero padding rows
    const bf16* row = in + (yy << 7);
    float vals[10];
    vals[0] = (xs > 0) ? (float)row[xs - 1] : 0.f;
    bf16x8 v8 = *(const bf16x8*)(row + xs);
#pragma unroll
    for (int j = 0; j < 8; j++) vals[1 + j] = (float)v8[j];
    vals[9] = (xs < 120) ? (float)row[xs + 8] : 0.f;
#pragma unroll
    for (int orow = 0; orow < 4; orow++) {
      int wrow = rr - orow;                      // compile-time under unroll
      if (wrow < 0 || wrow > 2) continue;
      float w0 = wv[wrow * 3 + 0], w1 = wv[wrow * 3 + 1], w2 = wv[wrow * 3 + 2];
#pragma unroll
      for (int i = 0; i < 8; i++)
        o[orow][i] += w0 * vals[i] + w1 * vals[i + 1] + w2 * vals[i + 2];
    }
  }
  float ss = 0.f;
  bf16* ob = out + (((size_t)(b * 576 + ch)) << 14);
#pragma unroll
  for (int r = 0; r < 4; r++) {
    bf16x8 ov;
#pragma unroll
    for (int i = 0; i < 8; i++) { ov[i] = (bf16)o[r][i]; ss += o[r][i] * o[r][i]; }
    *(bf16x8*)(ob + ((y0 + r) << 7) + xs) = ov;
  }
  if (ch < 384) {
#pragma unroll
    for (int off = 32; off; off >>= 1) ss += __shfl_down(ss, off);
    __shared__ float red[4];
    if ((tid & 63) == 0) red[tid >> 6] = ss;
    __syncthreads();
    if (tid == 0) atomicAdd(&sumsq[b * 384 + ch], red[0] + red[1] + red[2] + red[3]);
  }
}

// ------------------------------------------------- q k^T partials via MFMA
__global__ __launch_bounds__(256) void spart_kernel(
    const bf16* __restrict__ dwout, float* __restrict__ Spart) {
  int tid = threadIdx.x;
  int bh = blockIdx.y, split = blockIdx.x;
  int b = bh >> 3, h = bh & 7;
  int wave = tid >> 6, lane = tid & 63;
  int c0 = lane & 15, qd = lane >> 4;
  __shared__ float Sred[576];
  for (int i = tid; i < 576; i += 256) Sred[i] = 0.f;
  __syncthreads();
  const bf16* qb = dwout + (((size_t)(b * 576 + h * 24)) << 14);
  const bf16* kb = dwout + (((size_t)(b * 576 + 192 + h * 24)) << 14);
  int r0 = c0;
  int r1 = (16 + c0 < 24) ? (16 + c0) : 23;
  f32x4 a00 = {0.f,0.f,0.f,0.f}, a01 = {0.f,0.f,0.f,0.f};
  f32x4 a10 = {0.f,0.f,0.f,0.f}, a11 = {0.f,0.f,0.f,0.f};
  int base = (((split << 2) + wave) << 9) + (qd << 3);
  for (int t = 0; t < 16; t++) {
    int kk = base + (t << 5);
    bf16x8 qa0 = *(const bf16x8*)(qb + (((size_t)r0) << 14) + kk);
    bf16x8 qa1 = *(const bf16x8*)(qb + (((size_t)r1) << 14) + kk);
    bf16x8 ka0 = *(const bf16x8*)(kb + (((size_t)r0) << 14) + kk);
    bf16x8 ka1 = *(const bf16x8*)(kb + (((size_t)r1) << 14) + kk);
    a00 = __builtin_amdgcn_mfma_f32_16x16x32_bf16(qa0, ka0, a00, 0, 0, 0);
    a01 = __builtin_amdgcn_mfma_f32_16x16x32_bf16(qa0, ka1, a01, 0, 0, 0);
    a10 = __builtin_amdgcn_mfma_f32_16x16x32_bf16(qa1, ka0, a10, 0, 0, 0);
    a11 = __builtin_amdgcn_mfma_f32_16x16x32_bf16(qa1, ka1, a11, 0, 0, 0);
  }
  f32x4 accs[4] = {a00, a01, a10, a11};
#pragma unroll
  for (int mi = 0; mi < 2; mi++)
#pragma unroll
    for (int nj = 0; nj < 2; nj++) {
      f32x4 a = accs[mi * 2 + nj];
#pragma unroll
      for (int r = 0; r < 4; r++) {
        int rrow = (mi << 4) + (qd << 2) + r;
        int cc = (nj << 4) + c0;
        if (rrow < 24 && cc < 24) atomicAdd(&Sred[rrow * 24 + cc], a[r]);
      }
    }
  __syncthreads();
  float* outp = Spart + (size_t)(bh * 8 + split) * 576;
  for (int i = tid; i < 576; i += 256) outp[i] = Sred[i];
}

// ------------------------------------------------- normalize + softmax(24x24)
__global__ __launch_bounds__(576) void attn_kernel(
    const float* __restrict__ Spart, const float* __restrict__ sumsq,
    float* __restrict__ attn) {
  int bh = blockIdx.x, tid = threadIdx.x;
  int b = bh >> 3, h = bh & 7;
  int c = tid / 24, d = tid % 24;
  float s = 0.f;
  for (int sp = 0; sp < 8; sp++) s += Spart[(size_t)(bh * 8 + sp) * 576 + tid];
  float nq = fmaxf(sqrtf(sumsq[b * 384 + h * 24 + c]), 1e-12f);
  float nk = fmaxf(sqrtf(sumsq[b * 384 + 192 + h * 24 + d]), 1e-12f);
  s = s / (nq * nk) * 0.20412414523193154f;
  __shared__ float Sm[576];
  Sm[tid] = s;
  __syncthreads();
  float mx = -1e30f;
  for (int j = 0; j < 24; j++) mx = fmaxf(mx, Sm[c * 24 + j]);
  float Z = 0.f;
  for (int j = 0; j < 24; j++) Z += __expf(Sm[c * 24 + j] - mx);
  attn[(size_t)bh * 576 + tid] = __expf(s - mx) / Z;
}

// ------------------------------------------------- attn x v + gating -> gated_t panels
__global__ __launch_bounds__(256) void av_kernel(
    const bf16* __restrict__ dwout, const float* __restrict__ attn,
    const float* __restrict__ gates2, bf16* __restrict__ gated_t) {
  int tid = threadIdx.x;
  int bh = blockIdx.y;
  int b = bh >> 3, h = bh & 7;
  int n = blockIdx.x * 256 + tid;
  __shared__ float At[576];
  for (int i = tid; i < 576; i += 256) At[i] = attn[(size_t)bh * 576 + i];
  __syncthreads();
  const bf16* vb = dwout + (((size_t)(b * 576 + 384 + h * 24)) << 14) + n;
  float acc[24];
#pragma unroll
  for (int c = 0; c < 24; c++) acc[c] = 0.f;
#pragma unroll
  for (int d0 = 0; d0 < 24; d0 += 4) {
    float v0 = (float)vb[(size_t)(d0 + 0) << 14];
    float v1 = (float)vb[(size_t)(d0 + 1) << 14];
    float v2 = (float)vb[(size_t)(d0 + 2) << 14];
    float v3 = (float)vb[(size_t)(d0 + 3) << 14];
#pragma unroll
    for (int c = 0; c < 24; c++) {
      const float4* ap = (const float4*)&At[c * 24 + d0];
      acc[c] += ap->x * v0 + ap->y * v1 + ap->z * v2 + ap->w * v3;
    }
  }
  float g = gates2[(((size_t)(b * 8 + h)) << 14) + n];
#pragma unroll
  for (int ch = 0; ch < 3; ch++) {
    bf16x8 o;
#pragma unroll
    for (int i = 0; i < 8; i++) o[i] = (bf16)(acc[ch * 8 + i] * g);
    int c = h * 24 + ch * 8;                       // aligned to 8
    int kc = c >> 5, j8 = (c >> 3) & 3;
    size_t dst = (((size_t)b * 6 + kc) << 19) + ((size_t)(n >> 4) << 9)
               + (((j8 << 4) + ((n & 15) ^ (j8 << 1))) << 3);
    *(bf16x8*)(gated_t + dst) = o;
  }
}

// ---------------------------------------------------------------- launch
extern "C" void kernel_launch(void* const* d_in, const int* in_sizes, int n_in,
                              void* d_out, int out_size, void* d_ws, size_t ws_size,
                              hipStream_t stream) {
  const void* x_raw    = d_in[0];
  const void* qkvw_raw = d_in[1];
  const void* dww_raw  = d_in[2];
  const void* projw_raw= d_in[3];
  const void* rtm_raw  = d_in[4];
  const void* rta_raw  = d_in[5];
  const int*  task     = (const int*)d_in[6];
  char* ws = (char*)d_ws;

  bf16*  qkv_raw = (bf16*)(ws);                    // 150,994,944 B
  bf16*  gated_t = qkv_raw;                        // reuse (dead after dwconv)
  bf16*  dwout   = (bf16*)(ws + 150994944);        // 150,994,944 B
  float* gates2  = (float*)(ws + 301989888);       // 4,194,304 B
  float* sumsq   = (float*)(ws + 306184192);       // 12,288 B
  float* Spart   = (float*)(ws + 306196480);       // 1,179,648 B
  float* attn    = (float*)(ws + 307376128);       // 147,456 B
  int*   flag    = (int*)(ws + 307523584);         // 128 B pad
  bf16*  xt      = (bf16*)(ws + 307523712);        // 50,331,648 B
  bf16*  qkv_wb  = (bf16*)(ws + 357855360);        // 221,184 B
  bf16*  dw_wb   = (bf16*)(ws + 358076544);        // 10,368 B
  bf16*  proj_wb = (bf16*)(ws + 358086912);        // 73,728 B

  hipMemsetAsync(sumsq, 0, 8 * 384 * sizeof(float), stream);
  detect_kernel<<<1, 256, 0, stream>>>((const u32*)x_raw, flag);
  wconvert_kernel<<<dim3(54, 3), 256, 0, stream>>>(qkvw_raw, qkv_wb, dww_raw, dw_wb,
                                                   projw_raw, proj_wb, flag);
  // transpose (panel layout) with fused router
  transpose_kernel<<<dim3(128, 8), 256, 0, stream>>>(x_raw, xt, flag,
                                                     rtm_raw, rta_raw, task, gates2);
  wgemm2_kernel<<<dim3(6, 64, 8), 256, 0, stream>>>(qkv_wb, xt, qkv_raw, 576, flag, 0);
  // 8x4 patch per thread (round-5 proven best)
  dwconv_kernel<<<dim3(2, 576, 8), 256, 0, stream>>>(qkv_raw, dw_wb, dwout, sumsq);
  spart_kernel<<<dim3(8, 64), 256, 0, stream>>>(dwout, Spart);
  attn_kernel<<<64, 576, 0, stream>>>(Spart, sumsq, attn);
  av_kernel<<<dim3(64, 64), 256, 0, stream>>>(dwout, attn, gates2, gated_t);
  wgemm2_kernel<<<dim3(2, 64, 8), 256, 0, stream>>>(proj_wb, gated_t, d_out, 192, flag, 1);
}

// Round 8
// 415.556 us; speedup vs baseline: 1.0515x; 1.0515x over previous
//
#include <hip/hip_runtime.h>
#include <hip/hip_bf16.h>

typedef __bf16 bf16;
typedef __bf16 bf16x8 __attribute__((ext_vector_type(8)));
typedef __bf16 bf16x4 __attribute__((ext_vector_type(4)));
typedef float f32x4 __attribute__((ext_vector_type(4)));
typedef unsigned int u32;

#define NPIX 16384
#define CDIM 192

// Tiled-swizzled operand layout ("panel" layout), shared by xt, qkv_wb, proj_wb,
// gated_t:  element (row, k) of a [R][192] matrix lives at
//   panel(kc = k>>5) * R*32  +  (row>>4)*512  +  (slot)*8 + (k&7)
//   slot = j8*16 + ((row&15) ^ (j8<<1)),  j8 = (k>>3)&3
// This is exactly the LDS image the GEMM's slot8 fragment reads expect, so a
// linear gl2lds16 of 512-el groups reproduces the (0-conflict) LDS verbatim
// while every stage load is a contiguous, fully-coalesced 1KB.

// async 16B/lane global->LDS (lds base wave-uniform; HW adds lane*16 to LDS)
__device__ __forceinline__ void gl2lds16(const bf16* g, const bf16* l) {
  __builtin_amdgcn_global_load_lds(
      (const __attribute__((address_space(1))) u32*)(g),
      (__attribute__((address_space(3))) u32*)(l), 16, 0, 0);
}

// ------------------------------------------------- input dtype detector
__global__ __launch_bounds__(256) void detect_kernel(
    const u32* __restrict__ xw, int* __restrict__ flag) {
  int tid = threadIdx.x;
  int cnt = 0;
  for (int i = 0; i < 32; i++) {
    u32 w = xw[tid * 32 + i];
    u32 e = (w >> 7) & 0xFFu;   // exponent of low-half bf16
    if (e >= 0xC0u) cnt++;
  }
  for (int off = 32; off; off >>= 1) cnt += __shfl_down(cnt, off);
  __shared__ int red[4];
  if ((tid & 63) == 0) red[tid >> 6] = cnt;
  __syncthreads();
  if (tid == 0) *flag = (red[0] + red[1] + red[2] + red[3] >= 16) ? 1 : 0;
}

// ------------------------------------------------- weights -> bf16 (merged)
// qkv_w (M=576) and proj_w (M=192) are stored in panel layout; dw_w linear.
__global__ __launch_bounds__(256) void wconvert_kernel(
    const void* __restrict__ s0, bf16* __restrict__ d0,
    const void* __restrict__ s1, bf16* __restrict__ d1,
    const void* __restrict__ s2, bf16* __restrict__ d2,
    const int* __restrict__ flag) {
  int which = blockIdx.y;
  const void* src = which == 0 ? s0 : (which == 1 ? s1 : s2);
  bf16* dst = which == 0 ? d0 : (which == 1 ? d1 : d2);
  int n = which == 0 ? 110592 : (which == 1 ? 5184 : 36864);
  int base = (blockIdx.x * 256 + threadIdx.x) * 8;
  if (base >= n) return;
  bf16x8 o;
  if (*flag) {
    const float* s = (const float*)src;
    float4 lo = *(const float4*)(s + base);
    float4 hi = *(const float4*)(s + base + 4);
    o[0] = (bf16)lo.x; o[1] = (bf16)lo.y; o[2] = (bf16)lo.z; o[3] = (bf16)lo.w;
    o[4] = (bf16)hi.x; o[5] = (bf16)hi.y; o[6] = (bf16)hi.z; o[7] = (bf16)hi.w;
  } else {
    o = *(const bf16x8*)((const bf16*)src + base);
  }
  if (which != 1) {
    int M = (which == 0) ? 576 : 192;
    int m = base / 192, k = base - m * 192;          // k % 8 == 0
    int kc = k >> 5, j8 = (k >> 3) & 3;
    size_t dstoff = (size_t)kc * M * 32 + ((size_t)(m >> 4) << 9)
                  + (((j8 << 4) + ((m & 15) ^ (j8 << 1))) << 3);
    *(bf16x8*)(dst + dstoff) = o;
  } else {
    *(bf16x8*)(dst + base) = o;
  }
}

// ------------------------------------------------- x -> xt panels (+ fused router)
// Thread loads 8 c-rows x 4 n (coalesced); writes 4x 16B chunks in panel layout.
// Router fused: same x values dotted against W^T (LDS, broadcast reads) in f32,
// reduced shfl_xor(32) intra-wave then 4-way via LDS; identical top-2 gate math.
__global__ __launch_bounds__(256) void transpose_kernel(
    const void* __restrict__ xraw, bf16* __restrict__ xt,
    const int* __restrict__ flag, const void* __restrict__ wmain,
    const void* __restrict__ waux, const int* __restrict__ task,
    float* __restrict__ gates2) {
  __shared__ float wT[CDIM][8];      // 6 KB
  __shared__ float lred[4][128][8];  // 16 KB
  int t = threadIdx.x;
  int b = blockIdx.y;
  int n0 = blockIdx.x * 128;
  int f = *flag;
  const void* rw = (*task == 0) ? wmain : waux;
  for (int i = t; i < 8 * CDIM; i += 256) {
    int h = i / CDIM, c = i - h * CDIM;
    wT[c][h] = f ? ((const float*)rw)[i] : (float)((const bf16*)rw)[i];
  }
  __syncthreads();
  int nl = (t & 31) * 4;
  int cb = (t >> 5) * 8;             // 0..56
  float l[4][8];
#pragma unroll
  for (int j = 0; j < 4; j++)
#pragma unroll
    for (int h = 0; h < 8; h++) l[j][h] = 0.f;
  for (int ch = 0; ch < 3; ch++) {
    int c8 = ch * 64 + cb;
    float v[8][4];
    if (f) {
      const float* xp = (const float*)xraw + ((size_t)b * CDIM << 14) + n0 + nl;
#pragma unroll
      for (int i = 0; i < 8; i++) {
        float4 q = *(const float4*)(xp + ((size_t)(c8 + i) << 14));
        v[i][0] = q.x; v[i][1] = q.y; v[i][2] = q.z; v[i][3] = q.w;
      }
    } else {
      const bf16* xp = (const bf16*)xraw + ((size_t)b * CDIM << 14) + n0 + nl;
#pragma unroll
      for (int i = 0; i < 8; i++) {
        bf16x4 q = *(const bf16x4*)(xp + ((size_t)(c8 + i) << 14));
#pragma unroll
        for (int j = 0; j < 4; j++) v[i][j] = (float)q[j];
      }
    }
    // router partials
#pragma unroll
    for (int i = 0; i < 8; i++) {
      float4 wlo = *(const float4*)&wT[c8 + i][0];
      float4 whi = *(const float4*)&wT[c8 + i][4];
#pragma unroll
      for (int j = 0; j < 4; j++) {
        float xv = v[i][j];
        l[j][0] += xv * wlo.x; l[j][1] += xv * wlo.y;
        l[j][2] += xv * wlo.z; l[j][3] += xv * wlo.w;
        l[j][4] += xv * whi.x; l[j][5] += xv * whi.y;
        l[j][6] += xv * whi.z; l[j][7] += xv * whi.w;
      }
    }
    int kc = c8 >> 5, j8 = (c8 >> 3) & 3;
    size_t pb = (((size_t)b * 6 + kc) << 19);
#pragma unroll
    for (int j = 0; j < 4; j++) {
      bf16x8 o;
#pragma unroll
      for (int i = 0; i < 8; i++) o[i] = (bf16)v[i][j];
      int nn = n0 + nl + j;
      size_t dst = pb + ((size_t)(nn >> 4) << 9)
                 + (((j8 << 4) + ((nn & 15) ^ (j8 << 1))) << 3);
      *(bf16x8*)(xt + dst) = o;
    }
  }
  // ---- router reduce: g-bit0 is tid bit5 (intra-wave) -> shfl_xor 32
#pragma unroll
  for (int j = 0; j < 4; j++)
#pragma unroll
    for (int h = 0; h < 8; h++) l[j][h] += __shfl_xor(l[j][h], 32);
  int lane = t & 63, wid = t >> 6;
  if (lane < 32) {
#pragma unroll
    for (int j = 0; j < 4; j++) {
      *(float4*)&lred[wid][nl + j][0] = make_float4(l[j][0], l[j][1], l[j][2], l[j][3]);
      *(float4*)&lred[wid][nl + j][4] = make_float4(l[j][4], l[j][5], l[j][6], l[j][7]);
    }
  }
  __syncthreads();
  if (t < 128) {
    float lg[8];
#pragma unroll
    for (int h = 0; h < 8; h++)
      lg[h] = (lred[0][t][h] + lred[1][t][h]) + (lred[2][t][h] + lred[3][t][h]);
    int i1 = 0;
#pragma unroll
    for (int h = 1; h < 8; h++) if (lg[h] > lg[i1]) i1 = h;
    int i2 = (i1 == 0) ? 1 : 0;
#pragma unroll
    for (int h = 0; h < 8; h++) if (h != i1 && lg[h] > lg[i2]) i2 = h;
    float e = __expf(lg[i2] - lg[i1]);
    float g1 = 2.f / (1.f + e);
    float g2 = e * g1;
    float* gb = gates2 + (((size_t)b * 8) << 14) + n0 + t;
#pragma unroll
    for (int h = 0; h < 8; h++)
      gb[(size_t)h << 14] = (h == i1) ? g1 : ((h == i2) ? g2 : 0.f);
  }
}

// ------------------------------------------------- GEMM: panel-layout staging (round-5 proven)
// C[z][m][n] = sum_k A[m][k] * Xt[z][n][k].  Block 96m x 256n, BK=32, dbuf.
// Operands in panel layout -> every gl2lds16 stages a contiguous 1KB group.
// LDS image slot-swizzled (0 bank conflicts); swapped-operand epilogue ->
// 8B/16B vector stores. XCD swizzle: z = ord%8 -> one batch per XCD.
__global__ __launch_bounds__(256) void wgemm2_kernel(
    const bf16* __restrict__ A, const bf16* __restrict__ Xt,
    void* __restrict__ C, int M, const int* __restrict__ flag, int finalout) {
  __shared__ bf16 smem[22528];       // 45,056 B (2 buffers of 11264 el)
  int tid = threadIdx.x;
  int wave = tid >> 6, lane = tid & 63;
  int c0 = lane & 15, qd = lane >> 4;

  int nm = M / 96;                                   // 6 (qkv) or 2 (proj)
  int ord = blockIdx.x + nm * (blockIdx.y + (blockIdx.z << 6));
  int z = ord & 7;
  int local = ord >> 3;
  int mt = local % nm;
  int nt = local / nm;
  int m0 = mt * 96, n0 = nt << 8;

  const bf16* Xb = Xt + (size_t)z * CDIM * NPIX;
  size_t cbase = (size_t)z * M * NPIX;
  int Mx32 = M * 32;

  // frag-read slot: element offset of lane's 16B within a 16-row group
  int slot8 = ((qd << 4) + (c0 ^ (qd << 1))) << 3;

  f32x4 acc[6][4];
#pragma unroll
  for (int i = 0; i < 6; i++)
#pragma unroll
    for (int j = 0; j < 4; j++) acc[i][j] = {0.f, 0.f, 0.f, 0.f};

  auto STAGE = [&](int bb, int kc) {
    const bf16* As = A + (size_t)kc * Mx32 + mt * 3072 + (lane << 3);
    const bf16* Bs = Xb + ((size_t)kc << 19)
                   + ((size_t)((nt << 4) + (wave << 2)) << 9) + (lane << 3);
    gl2lds16(As + (wave << 9), smem + bb + (wave << 9));
    if (wave < 2) gl2lds16(As + ((4 + wave) << 9), smem + bb + ((4 + wave) << 9));
    const bf16* bl = smem + bb + 3072 + (wave << 11);
    gl2lds16(Bs,        bl);
    gl2lds16(Bs +  512, bl + 512);
    gl2lds16(Bs + 1024, bl + 1024);
    gl2lds16(Bs + 1536, bl + 1536);
  };

  int bb = 0;
  STAGE(0, 0);
  __syncthreads();
  for (int t = 0; t < 6; t++) {
    if (t < 5) STAGE(bb ^ 11264, t + 1);             // prefetch next K-step
    bf16x8 af[6], bfr[4];
#pragma unroll
    for (int mi = 0; mi < 6; mi++)
      af[mi] = *(const bf16x8*)(smem + bb + mi * 512 + slot8);
#pragma unroll
    for (int nj = 0; nj < 4; nj++)
      bfr[nj] = *(const bf16x8*)(smem + bb + 3072 + (wave << 11) + nj * 512 + slot8);
#pragma unroll
    for (int mi = 0; mi < 6; mi++)
#pragma unroll
      for (int nj = 0; nj < 4; nj++)
        acc[mi][nj] = __builtin_amdgcn_mfma_f32_16x16x32_bf16(bfr[nj], af[mi], acc[mi][nj], 0, 0, 0);
    if (t < 5) { __syncthreads(); bb ^= 11264; }     // drains the prefetch
  }

  // epilogue: lane holds C[m = m0+mi*16+c0][n = n_base+nj*16 .. +3]
  int f32o = finalout && (*flag);
  int n_base = n0 + (wave << 6) + (qd << 2);
#pragma unroll
  for (int mi = 0; mi < 6; mi++) {
    size_t rowb = cbase + ((size_t)(m0 + (mi << 4) + c0) << 14) + n_base;
#pragma unroll
    for (int nj = 0; nj < 4; nj++) {
      if (f32o) {
        *(float4*)((float*)C + rowb + (nj << 4)) =
            make_float4(acc[mi][nj][0], acc[mi][nj][1], acc[mi][nj][2], acc[mi][nj][3]);
      } else {
        bf16x4 o;
        o[0] = (bf16)acc[mi][nj][0]; o[1] = (bf16)acc[mi][nj][1];
        o[2] = (bf16)acc[mi][nj][2]; o[3] = (bf16)acc[mi][nj][3];
        *(bf16x4*)((bf16*)C + rowb + (nj << 4)) = o;
      }
    }
  }
}

// ----------------------------------------------- depthwise 3x3 + q/k sumsq
// 8x4 patch per thread + SHFL EDGES: horizontal neighbors come from adjacent
// lanes' registers (lane l's vals[0] = lane l-1's vals[8]) instead of 12
// predicated scalar loads -> 7 VMEM insts/thread instead of 19. Cross-group
// shfl results land only at lx==0/15 where the image boundary forces 0.
__global__ __launch_bounds__(256) void dwconv_kernel(
    const bf16* __restrict__ qkv, const bf16* __restrict__ w9,
    bf16* __restrict__ out, float* __restrict__ sumsq) {
  int tid = threadIdx.x;
  int ch = blockIdx.y, b = blockIdx.z;
  int lx = tid & 15;
  int xs = lx << 3;                              // 0..120
  int y0 = (blockIdx.x << 6) + ((tid >> 4) << 2);  // 4-row group
  const bf16* in = qkv + (((size_t)(b * 576 + ch)) << 14);
  float wv[9];
#pragma unroll
  for (int i = 0; i < 9; i++) wv[i] = (float)w9[ch * 9 + i];
  float o[4][8];
#pragma unroll
  for (int r = 0; r < 4; r++)
#pragma unroll
    for (int i = 0; i < 8; i++) o[r][i] = 0.f;
#pragma unroll
  for (int rr = 0; rr < 6; rr++) {
    int yy = y0 - 1 + rr;
    if (yy < 0 || yy > 127) continue;            // zero padding rows (uniform per 16-lane group)
    const bf16* row = in + (yy << 7);
    bf16x8 v8 = *(const bf16x8*)(row + xs);
    float vals[10];
#pragma unroll
    for (int j = 0; j < 8; j++) vals[1 + j] = (float)v8[j];
    float lf = __shfl_up(vals[8], 1);            // lane l-1's px[xs-1]
    float rt = __shfl_down(vals[1], 1);          // lane l+1's px[xs+8]
    vals[0] = (lx > 0)  ? lf : 0.f;
    vals[9] = (lx < 15) ? rt : 0.f;
#pragma unroll
    for (int orow = 0; orow < 4; orow++) {
      int wrow = rr - orow;                      // compile-time under unroll
      if (wrow < 0 || wrow > 2) continue;
      float w0 = wv[wrow * 3 + 0], w1 = wv[wrow * 3 + 1], w2 = wv[wrow * 3 + 2];
#pragma unroll
      for (int i = 0; i < 8; i++)
        o[orow][i] += w0 * vals[i] + w1 * vals[i + 1] + w2 * vals[i + 2];
    }
  }
  float ss = 0.f;
  bf16* ob = out + (((size_t)(b * 576 + ch)) << 14);
#pragma unroll
  for (int r = 0; r < 4; r++) {
    bf16x8 ov;
#pragma unroll
    for (int i = 0; i < 8; i++) { ov[i] = (bf16)o[r][i]; ss += o[r][i] * o[r][i]; }
    *(bf16x8*)(ob + ((y0 + r) << 7) + xs) = ov;
  }
  if (ch < 384) {
#pragma unroll
    for (int off = 32; off; off >>= 1) ss += __shfl_down(ss, off);
    __shared__ float red[4];
    if ((tid & 63) == 0) red[tid >> 6] = ss;
    __syncthreads();
    if (tid == 0) atomicAdd(&sumsq[b * 384 + ch], red[0] + red[1] + red[2] + red[3]);
  }
}

// ------------------------------------------------- q k^T partials via MFMA
__global__ __launch_bounds__(256) void spart_kernel(
    const bf16* __restrict__ dwout, float* __restrict__ Spart) {
  int tid = threadIdx.x;
  int bh = blockIdx.y, split = blockIdx.x;
  int b = bh >> 3, h = bh & 7;
  int wave = tid >> 6, lane = tid & 63;
  int c0 = lane & 15, qd = lane >> 4;
  __shared__ float Sred[576];
  for (int i = tid; i < 576; i += 256) Sred[i] = 0.f;
  __syncthreads();
  const bf16* qb = dwout + (((size_t)(b * 576 + h * 24)) << 14);
  const bf16* kb = dwout + (((size_t)(b * 576 + 192 + h * 24)) << 14);
  int r0 = c0;
  int r1 = (16 + c0 < 24) ? (16 + c0) : 23;
  f32x4 a00 = {0.f,0.f,0.f,0.f}, a01 = {0.f,0.f,0.f,0.f};
  f32x4 a10 = {0.f,0.f,0.f,0.f}, a11 = {0.f,0.f,0.f,0.f};
  int base = (((split << 2) + wave) << 9) + (qd << 3);
  for (int t = 0; t < 16; t++) {
    int kk = base + (t << 5);
    bf16x8 qa0 = *(const bf16x8*)(qb + (((size_t)r0) << 14) + kk);
    bf16x8 qa1 = *(const bf16x8*)(qb + (((size_t)r1) << 14) + kk);
    bf16x8 ka0 = *(const bf16x8*)(kb + (((size_t)r0) << 14) + kk);
    bf16x8 ka1 = *(const bf16x8*)(kb + (((size_t)r1) << 14) + kk);
    a00 = __builtin_amdgcn_mfma_f32_16x16x32_bf16(qa0, ka0, a00, 0, 0, 0);
    a01 = __builtin_amdgcn_mfma_f32_16x16x32_bf16(qa0, ka1, a01, 0, 0, 0);
    a10 = __builtin_amdgcn_mfma_f32_16x16x32_bf16(qa1, ka0, a10, 0, 0, 0);
    a11 = __builtin_amdgcn_mfma_f32_16x16x32_bf16(qa1, ka1, a11, 0, 0, 0);
  }
  f32x4 accs[4] = {a00, a01, a10, a11};
#pragma unroll
  for (int mi = 0; mi < 2; mi++)
#pragma unroll
    for (int nj = 0; nj < 2; nj++) {
      f32x4 a = accs[mi * 2 + nj];
#pragma unroll
      for (int r = 0; r < 4; r++) {
        int rrow = (mi << 4) + (qd << 2) + r;
        int cc = (nj << 4) + c0;
        if (rrow < 24 && cc < 24) atomicAdd(&Sred[rrow * 24 + cc], a[r]);
      }
    }
  __syncthreads();
  float* outp = Spart + (size_t)(bh * 8 + split) * 576;
  for (int i = tid; i < 576; i += 256) outp[i] = Sred[i];
}

// ------------------------------------------------- normalize + softmax(24x24)
__global__ __launch_bounds__(576) void attn_kernel(
    const float* __restrict__ Spart, const float* __restrict__ sumsq,
    float* __restrict__ attn) {
  int bh = blockIdx.x, tid = threadIdx.x;
  int b = bh >> 3, h = bh & 7;
  int c = tid / 24, d = tid % 24;
  float s = 0.f;
  for (int sp = 0; sp < 8; sp++) s += Spart[(size_t)(bh * 8 + sp) * 576 + tid];
  float nq = fmaxf(sqrtf(sumsq[b * 384 + h * 24 + c]), 1e-12f);
  float nk = fmaxf(sqrtf(sumsq[b * 384 + 192 + h * 24 + d]), 1e-12f);
  s = s / (nq * nk) * 0.20412414523193154f;
  __shared__ float Sm[576];
  Sm[tid] = s;
  __syncthreads();
  float mx = -1e30f;
  for (int j = 0; j < 24; j++) mx = fmaxf(mx, Sm[c * 24 + j]);
  float Z = 0.f;
  for (int j = 0; j < 24; j++) Z += __expf(Sm[c * 24 + j] - mx);
  attn[(size_t)bh * 576 + tid] = __expf(s - mx) / Z;
}

// ------------------------------------------------- attn x v + gating -> gated_t panels
__global__ __launch_bounds__(256) void av_kernel(
    const bf16* __restrict__ dwout, const float* __restrict__ attn,
    const float* __restrict__ gates2, bf16* __restrict__ gated_t) {
  int tid = threadIdx.x;
  int bh = blockIdx.y;
  int b = bh >> 3, h = bh & 7;
  int n = blockIdx.x * 256 + tid;
  __shared__ float At[576];
  for (int i = tid; i < 576; i += 256) At[i] = attn[(size_t)bh * 576 + i];
  __syncthreads();
  const bf16* vb = dwout + (((size_t)(b * 576 + 384 + h * 24)) << 14) + n;
  float acc[24];
#pragma unroll
  for (int c = 0; c < 24; c++) acc[c] = 0.f;
#pragma unroll
  for (int d0 = 0; d0 < 24; d0 += 4) {
    float v0 = (float)vb[(size_t)(d0 + 0) << 14];
    float v1 = (float)vb[(size_t)(d0 + 1) << 14];
    float v2 = (float)vb[(size_t)(d0 + 2) << 14];
    float v3 = (float)vb[(size_t)(d0 + 3) << 14];
#pragma unroll
    for (int c = 0; c < 24; c++) {
      const float4* ap = (const float4*)&At[c * 24 + d0];
      acc[c] += ap->x * v0 + ap->y * v1 + ap->z * v2 + ap->w * v3;
    }
  }
  float g = gates2[(((size_t)(b * 8 + h)) << 14) + n];
#pragma unroll
  for (int ch = 0; ch < 3; ch++) {
    bf16x8 o;
#pragma unroll
    for (int i = 0; i < 8; i++) o[i] = (bf16)(acc[ch * 8 + i] * g);
    int c = h * 24 + ch * 8;                       // aligned to 8
    int kc = c >> 5, j8 = (c >> 3) & 3;
    size_t dst = (((size_t)b * 6 + kc) << 19) + ((size_t)(n >> 4) << 9)
               + (((j8 << 4) + ((n & 15) ^ (j8 << 1))) << 3);
    *(bf16x8*)(gated_t + dst) = o;
  }
}

// ---------------------------------------------------------------- launch
extern "C" void kernel_launch(void* const* d_in, const int* in_sizes, int n_in,
                              void* d_out, int out_size, void* d_ws, size_t ws_size,
                              hipStream_t stream) {
  const void* x_raw    = d_in[0];
  const void* qkvw_raw = d_in[1];
  const void* dww_raw  = d_in[2];
  const void* projw_raw= d_in[3];
  const void* rtm_raw  = d_in[4];
  const void* rta_raw  = d_in[5];
  const int*  task     = (const int*)d_in[6];
  char* ws = (char*)d_ws;

  bf16*  qkv_raw = (bf16*)(ws);                    // 150,994,944 B
  bf16*  gated_t = qkv_raw;                        // reuse (dead after dwconv)
  bf16*  dwout   = (bf16*)(ws + 150994944);        // 150,994,944 B
  float* gates2  = (float*)(ws + 301989888);       // 4,194,304 B
  float* sumsq   = (float*)(ws + 306184192);       // 12,288 B
  float* Spart   = (float*)(ws + 306196480);       // 1,179,648 B
  float* attn    = (float*)(ws + 307376128);       // 147,456 B
  int*   flag    = (int*)(ws + 307523584);         // 128 B pad
  bf16*  xt      = (bf16*)(ws + 307523712);        // 50,331,648 B
  bf16*  qkv_wb  = (bf16*)(ws + 357855360);        // 221,184 B
  bf16*  dw_wb   = (bf16*)(ws + 358076544);        // 10,368 B
  bf16*  proj_wb = (bf16*)(ws + 358086912);        // 73,728 B

  hipMemsetAsync(sumsq, 0, 8 * 384 * sizeof(float), stream);
  detect_kernel<<<1, 256, 0, stream>>>((const u32*)x_raw, flag);
  wconvert_kernel<<<dim3(54, 3), 256, 0, stream>>>(qkvw_raw, qkv_wb, dww_raw, dw_wb,
                                                   projw_raw, proj_wb, flag);
  // transpose (panel layout) with fused router
  transpose_kernel<<<dim3(128, 8), 256, 0, stream>>>(x_raw, xt, flag,
                                                     rtm_raw, rta_raw, task, gates2);
  wgemm2_kernel<<<dim3(6, 64, 8), 256, 0, stream>>>(qkv_wb, xt, qkv_raw, 576, flag, 0);
  // 8x4 patch per thread, shfl edges
  dwconv_kernel<<<dim3(2, 576, 8), 256, 0, stream>>>(qkv_raw, dw_wb, dwout, sumsq);
  spart_kernel<<<dim3(8, 64), 256, 0, stream>>>(dwout, Spart);
  attn_kernel<<<64, 576, 0, stream>>>(Spart, sumsq, attn);
  av_kernel<<<dim3(64, 64), 256, 0, stream>>>(dwout, attn, gates2, gated_t);
  wgemm2_kernel<<<dim3(2, 64, 8), 256, 0, stream>>>(proj_wb, gated_t, d_out, 192, flag, 1);
}

// Round 9
// 412.262 us; speedup vs baseline: 1.0599x; 1.0080x over previous
//
#include <hip/hip_runtime.h>
#include <hip/hip_bf16.h>

typedef __bf16 bf16;
typedef __bf16 bf16x8 __attribute__((ext_vector_type(8)));
typedef __bf16 bf16x4 __attribute__((ext_vector_type(4)));
typedef float f32x4 __attribute__((ext_vector_type(4)));
typedef unsigned int u32;

#define NPIX 16384
#define CDIM 192

// Tiled-swizzled operand layout ("panel" layout), shared by xt, qkv_wb, proj_wb,
// gated_t:  element (row, k) of a [R][192] matrix lives at
//   panel(kc = k>>5) * R*32  +  (row>>4)*512  +  (slot)*8 + (k&7)
//   slot = j8*16 + ((row&15) ^ (j8<<1)),  j8 = (k>>3)&3
// This is exactly the LDS image the GEMM's slot8 fragment reads expect, so a
// linear gl2lds16 of 512-el groups reproduces the (0-conflict) LDS verbatim
// while every stage load is a contiguous, fully-coalesced 1KB.

// async 16B/lane global->LDS (lds base wave-uniform; HW adds lane*16 to LDS)
__device__ __forceinline__ void gl2lds16(const bf16* g, const bf16* l) {
  __builtin_amdgcn_global_load_lds(
      (const __attribute__((address_space(1))) u32*)(g),
      (__attribute__((address_space(3))) u32*)(l), 16, 0, 0);
}

// ------------------------------------------------- input dtype detector
__global__ __launch_bounds__(256) void detect_kernel(
    const u32* __restrict__ xw, int* __restrict__ flag) {
  int tid = threadIdx.x;
  int cnt = 0;
  for (int i = 0; i < 32; i++) {
    u32 w = xw[tid * 32 + i];
    u32 e = (w >> 7) & 0xFFu;   // exponent of low-half bf16
    if (e >= 0xC0u) cnt++;
  }
  for (int off = 32; off; off >>= 1) cnt += __shfl_down(cnt, off);
  __shared__ int red[4];
  if ((tid & 63) == 0) red[tid >> 6] = cnt;
  __syncthreads();
  if (tid == 0) *flag = (red[0] + red[1] + red[2] + red[3] >= 16) ? 1 : 0;
}

// ------------------------------------------------- weights -> bf16 (merged)
// qkv_w (M=576) and proj_w (M=192) are stored in panel layout; dw_w linear.
__global__ __launch_bounds__(256) void wconvert_kernel(
    const void* __restrict__ s0, bf16* __restrict__ d0,
    const void* __restrict__ s1, bf16* __restrict__ d1,
    const void* __restrict__ s2, bf16* __restrict__ d2,
    const int* __restrict__ flag) {
  int which = blockIdx.y;
  const void* src = which == 0 ? s0 : (which == 1 ? s1 : s2);
  bf16* dst = which == 0 ? d0 : (which == 1 ? d1 : d2);
  int n = which == 0 ? 110592 : (which == 1 ? 5184 : 36864);
  int base = (blockIdx.x * 256 + threadIdx.x) * 8;
  if (base >= n) return;
  bf16x8 o;
  if (*flag) {
    const float* s = (const float*)src;
    float4 lo = *(const float4*)(s + base);
    float4 hi = *(const float4*)(s + base + 4);
    o[0] = (bf16)lo.x; o[1] = (bf16)lo.y; o[2] = (bf16)lo.z; o[3] = (bf16)lo.w;
    o[4] = (bf16)hi.x; o[5] = (bf16)hi.y; o[6] = (bf16)hi.z; o[7] = (bf16)hi.w;
  } else {
    o = *(const bf16x8*)((const bf16*)src + base);
  }
  if (which != 1) {
    int M = (which == 0) ? 576 : 192;
    int m = base / 192, k = base - m * 192;          // k % 8 == 0
    int kc = k >> 5, j8 = (k >> 3) & 3;
    size_t dstoff = (size_t)kc * M * 32 + ((size_t)(m >> 4) << 9)
                  + (((j8 << 4) + ((m & 15) ^ (j8 << 1))) << 3);
    *(bf16x8*)(dst + dstoff) = o;
  } else {
    *(bf16x8*)(dst + base) = o;
  }
}

// ------------------------------------------------- x -> xt panels (+ fused router)
// Thread loads 8 c-rows x 4 n (coalesced); writes 4x 16B chunks in panel layout.
// Router fused: same x values dotted against W^T (LDS, broadcast reads) in f32,
// reduced shfl_xor(32) intra-wave then 4-way via LDS; identical top-2 gate math.
__global__ __launch_bounds__(256) void transpose_kernel(
    const void* __restrict__ xraw, bf16* __restrict__ xt,
    const int* __restrict__ flag, const void* __restrict__ wmain,
    const void* __restrict__ waux, const int* __restrict__ task,
    float* __restrict__ gates2) {
  __shared__ float wT[CDIM][8];      // 6 KB
  __shared__ float lred[4][128][8];  // 16 KB
  int t = threadIdx.x;
  int b = blockIdx.y;
  int n0 = blockIdx.x * 128;
  int f = *flag;
  const void* rw = (*task == 0) ? wmain : waux;
  for (int i = t; i < 8 * CDIM; i += 256) {
    int h = i / CDIM, c = i - h * CDIM;
    wT[c][h] = f ? ((const float*)rw)[i] : (float)((const bf16*)rw)[i];
  }
  __syncthreads();
  int nl = (t & 31) * 4;
  int cb = (t >> 5) * 8;             // 0..56
  float l[4][8];
#pragma unroll
  for (int j = 0; j < 4; j++)
#pragma unroll
    for (int h = 0; h < 8; h++) l[j][h] = 0.f;
  for (int ch = 0; ch < 3; ch++) {
    int c8 = ch * 64 + cb;
    float v[8][4];
    if (f) {
      const float* xp = (const float*)xraw + ((size_t)b * CDIM << 14) + n0 + nl;
#pragma unroll
      for (int i = 0; i < 8; i++) {
        float4 q = *(const float4*)(xp + ((size_t)(c8 + i) << 14));
        v[i][0] = q.x; v[i][1] = q.y; v[i][2] = q.z; v[i][3] = q.w;
      }
    } else {
      const bf16* xp = (const bf16*)xraw + ((size_t)b * CDIM << 14) + n0 + nl;
#pragma unroll
      for (int i = 0; i < 8; i++) {
        bf16x4 q = *(const bf16x4*)(xp + ((size_t)(c8 + i) << 14));
#pragma unroll
        for (int j = 0; j < 4; j++) v[i][j] = (float)q[j];
      }
    }
    // router partials
#pragma unroll
    for (int i = 0; i < 8; i++) {
      float4 wlo = *(const float4*)&wT[c8 + i][0];
      float4 whi = *(const float4*)&wT[c8 + i][4];
#pragma unroll
      for (int j = 0; j < 4; j++) {
        float xv = v[i][j];
        l[j][0] += xv * wlo.x; l[j][1] += xv * wlo.y;
        l[j][2] += xv * wlo.z; l[j][3] += xv * wlo.w;
        l[j][4] += xv * whi.x; l[j][5] += xv * whi.y;
        l[j][6] += xv * whi.z; l[j][7] += xv * whi.w;
      }
    }
    int kc = c8 >> 5, j8 = (c8 >> 3) & 3;
    size_t pb = (((size_t)b * 6 + kc) << 19);
#pragma unroll
    for (int j = 0; j < 4; j++) {
      bf16x8 o;
#pragma unroll
      for (int i = 0; i < 8; i++) o[i] = (bf16)v[i][j];
      int nn = n0 + nl + j;
      size_t dst = pb + ((size_t)(nn >> 4) << 9)
                 + (((j8 << 4) + ((nn & 15) ^ (j8 << 1))) << 3);
      *(bf16x8*)(xt + dst) = o;
    }
  }
  // ---- router reduce: g-bit0 is tid bit5 (intra-wave) -> shfl_xor 32
#pragma unroll
  for (int j = 0; j < 4; j++)
#pragma unroll
    for (int h = 0; h < 8; h++) l[j][h] += __shfl_xor(l[j][h], 32);
  int lane = t & 63, wid = t >> 6;
  if (lane < 32) {
#pragma unroll
    for (int j = 0; j < 4; j++) {
      *(float4*)&lred[wid][nl + j][0] = make_float4(l[j][0], l[j][1], l[j][2], l[j][3]);
      *(float4*)&lred[wid][nl + j][4] = make_float4(l[j][4], l[j][5], l[j][6], l[j][7]);
    }
  }
  __syncthreads();
  if (t < 128) {
    float lg[8];
#pragma unroll
    for (int h = 0; h < 8; h++)
      lg[h] = (lred[0][t][h] + lred[1][t][h]) + (lred[2][t][h] + lred[3][t][h]);
    int i1 = 0;
#pragma unroll
    for (int h = 1; h < 8; h++) if (lg[h] > lg[i1]) i1 = h;
    int i2 = (i1 == 0) ? 1 : 0;
#pragma unroll
    for (int h = 0; h < 8; h++) if (h != i1 && lg[h] > lg[i2]) i2 = h;
    float e = __expf(lg[i2] - lg[i1]);
    float g1 = 2.f / (1.f + e);
    float g2 = e * g1;
    float* gb = gates2 + (((size_t)b * 8) << 14) + n0 + t;
#pragma unroll
    for (int h = 0; h < 8; h++)
      gb[(size_t)h << 14] = (h == i1) ? g1 : ((h == i2) ? g2 : 0.f);
  }
}

// ------------------------------------------------- GEMM v8: 3-buffer ring, counted vmcnt
// C[z][m][n] = sum_k A[m][k] * Xt[z][n][k].  Block 96m x 256n, BK=32.
// T3/T4: depth-2 prefetch into a 3-buffer LDS ring; per K-step
//   s_waitcnt vmcnt(5) -> s_barrier -> STAGE(kc+2) -> ds_read/MFMA(kc)
// so stage loads stay in flight across ~2 compute phases (never drained to 0
// until the last step). Waves issue 5 or 6 loads/stage (FIFO vmcnt retirement:
// vmcnt(5) guarantees the current buffer's loads retired for both groups).
// STAGE sits AFTER the barrier: the buffer it overwrites was read in iter t-1,
// and every wave's t-1 reads completed (lgkm-waited before its MFMAs) before
// that wave reached this barrier. Panel layout: every gl2lds16 is a contiguous
// 1KB group; LDS image slot-swizzled (0 bank conflicts). XCD swizzle z=ord%8.
__global__ __launch_bounds__(256) void wgemm2_kernel(
    const bf16* __restrict__ A, const bf16* __restrict__ Xt,
    void* __restrict__ C, int M, const int* __restrict__ flag, int finalout) {
  __shared__ bf16 smem[33792];       // 67,584 B (3 buffers of 11264 el)
  int tid = threadIdx.x;
  int wave = tid >> 6, lane = tid & 63;
  int c0 = lane & 15, qd = lane >> 4;

  int nm = M / 96;                                   // 6 (qkv) or 2 (proj)
  int ord = blockIdx.x + nm * (blockIdx.y + (blockIdx.z << 6));
  int z = ord & 7;
  int local = ord >> 3;
  int mt = local % nm;
  int nt = local / nm;
  int m0 = mt * 96, n0 = nt << 8;

  const bf16* Xb = Xt + (size_t)z * CDIM * NPIX;
  size_t cbase = (size_t)z * M * NPIX;
  int Mx32 = M * 32;

  // frag-read slot: element offset of lane's 16B within a 16-row group
  int slot8 = ((qd << 4) + (c0 ^ (qd << 1))) << 3;

  f32x4 acc[6][4];
#pragma unroll
  for (int i = 0; i < 6; i++)
#pragma unroll
    for (int j = 0; j < 4; j++) acc[i][j] = {0.f, 0.f, 0.f, 0.f};

  auto STAGE = [&](int bufi, int kc) {
    int bb = bufi * 11264;
    const bf16* As = A + (size_t)kc * Mx32 + mt * 3072 + (lane << 3);
    const bf16* Bs = Xb + ((size_t)kc << 19)
                   + ((size_t)((nt << 4) + (wave << 2)) << 9) + (lane << 3);
    gl2lds16(As + (wave << 9), smem + bb + (wave << 9));
    if (wave < 2) gl2lds16(As + ((4 + wave) << 9), smem + bb + ((4 + wave) << 9));
    const bf16* bl = smem + bb + 3072 + (wave << 11);
    gl2lds16(Bs,        bl);
    gl2lds16(Bs +  512, bl + 512);
    gl2lds16(Bs + 1024, bl + 1024);
    gl2lds16(Bs + 1536, bl + 1536);
  };

  STAGE(0, 0);
  STAGE(1, 1);
#pragma unroll
  for (int t = 0; t < 6; t++) {
    if (t < 5) asm volatile("s_waitcnt vmcnt(5)" ::: "memory");
    else       asm volatile("s_waitcnt vmcnt(0)" ::: "memory");
    __builtin_amdgcn_sched_barrier(0);
    __builtin_amdgcn_s_barrier();
    __builtin_amdgcn_sched_barrier(0);
    if (t < 4) STAGE((t + 2) % 3, t + 2);            // overwrites buf read at t-1
    int bb = (t % 3) * 11264;
    bf16x8 af[6], bfr[4];
#pragma unroll
    for (int mi = 0; mi < 6; mi++)
      af[mi] = *(const bf16x8*)(smem + bb + mi * 512 + slot8);
#pragma unroll
    for (int nj = 0; nj < 4; nj++)
      bfr[nj] = *(const bf16x8*)(smem + bb + 3072 + (wave << 11) + nj * 512 + slot8);
#pragma unroll
    for (int mi = 0; mi < 6; mi++)
#pragma unroll
      for (int nj = 0; nj < 4; nj++)
        acc[mi][nj] = __builtin_amdgcn_mfma_f32_16x16x32_bf16(bfr[nj], af[mi], acc[mi][nj], 0, 0, 0);
  }

  // epilogue: lane holds C[m = m0+mi*16+c0][n = n_base+nj*16 .. +3]
  int f32o = finalout && (*flag);
  int n_base = n0 + (wave << 6) + (qd << 2);
#pragma unroll
  for (int mi = 0; mi < 6; mi++) {
    size_t rowb = cbase + ((size_t)(m0 + (mi << 4) + c0) << 14) + n_base;
#pragma unroll
    for (int nj = 0; nj < 4; nj++) {
      if (f32o) {
        *(float4*)((float*)C + rowb + (nj << 4)) =
            make_float4(acc[mi][nj][0], acc[mi][nj][1], acc[mi][nj][2], acc[mi][nj][3]);
      } else {
        bf16x4 o;
        o[0] = (bf16)acc[mi][nj][0]; o[1] = (bf16)acc[mi][nj][1];
        o[2] = (bf16)acc[mi][nj][2]; o[3] = (bf16)acc[mi][nj][3];
        *(bf16x4*)((bf16*)C + rowb + (nj << 4)) = o;
      }
    }
  }
}

// ----------------------------------------------- depthwise 3x3 + q/k sumsq
// 8x4 patch per thread + SHFL EDGES: horizontal neighbors come from adjacent
// lanes' registers (lane l's vals[0] = lane l-1's vals[8]) instead of 12
// predicated scalar loads -> 7 VMEM insts/thread instead of 19. Cross-group
// shfl results land only at lx==0/15 where the image boundary forces 0.
__global__ __launch_bounds__(256) void dwconv_kernel(
    const bf16* __restrict__ qkv, const bf16* __restrict__ w9,
    bf16* __restrict__ out, float* __restrict__ sumsq) {
  int tid = threadIdx.x;
  int ch = blockIdx.y, b = blockIdx.z;
  int lx = tid & 15;
  int xs = lx << 3;                              // 0..120
  int y0 = (blockIdx.x << 6) + ((tid >> 4) << 2);  // 4-row group
  const bf16* in = qkv + (((size_t)(b * 576 + ch)) << 14);
  float wv[9];
#pragma unroll
  for (int i = 0; i < 9; i++) wv[i] = (float)w9[ch * 9 + i];
  float o[4][8];
#pragma unroll
  for (int r = 0; r < 4; r++)
#pragma unroll
    for (int i = 0; i < 8; i++) o[r][i] = 0.f;
#pragma unroll
  for (int rr = 0; rr < 6; rr++) {
    int yy = y0 - 1 + rr;
    if (yy < 0 || yy > 127) continue;            // zero padding rows (uniform per 16-lane group)
    const bf16* row = in + (yy << 7);
    bf16x8 v8 = *(const bf16x8*)(row + xs);
    float vals[10];
#pragma unroll
    for (int j = 0; j < 8; j++) vals[1 + j] = (float)v8[j];
    float lf = __shfl_up(vals[8], 1);            // lane l-1's px[xs-1]
    float rt = __shfl_down(vals[1], 1);          // lane l+1's px[xs+8]
    vals[0] = (lx > 0)  ? lf : 0.f;
    vals[9] = (lx < 15) ? rt : 0.f;
#pragma unroll
    for (int orow = 0; orow < 4; orow++) {
      int wrow = rr - orow;                      // compile-time under unroll
      if (wrow < 0 || wrow > 2) continue;
      float w0 = wv[wrow * 3 + 0], w1 = wv[wrow * 3 + 1], w2 = wv[wrow * 3 + 2];
#pragma unroll
      for (int i = 0; i < 8; i++)
        o[orow][i] += w0 * vals[i] + w1 * vals[i + 1] + w2 * vals[i + 2];
    }
  }
  float ss = 0.f;
  bf16* ob = out + (((size_t)(b * 576 + ch)) << 14);
#pragma unroll
  for (int r = 0; r < 4; r++) {
    bf16x8 ov;
#pragma unroll
    for (int i = 0; i < 8; i++) { ov[i] = (bf16)o[r][i]; ss += o[r][i] * o[r][i]; }
    *(bf16x8*)(ob + ((y0 + r) << 7) + xs) = ov;
  }
  if (ch < 384) {
#pragma unroll
    for (int off = 32; off; off >>= 1) ss += __shfl_down(ss, off);
    __shared__ float red[4];
    if ((tid & 63) == 0) red[tid >> 6] = ss;
    __syncthreads();
    if (tid == 0) atomicAdd(&sumsq[b * 384 + ch], red[0] + red[1] + red[2] + red[3]);
  }
}

// ------------------------------------------------- q k^T partials via MFMA
__global__ __launch_bounds__(256) void spart_kernel(
    const bf16* __restrict__ dwout, float* __restrict__ Spart) {
  int tid = threadIdx.x;
  int bh = blockIdx.y, split = blockIdx.x;
  int b = bh >> 3, h = bh & 7;
  int wave = tid >> 6, lane = tid & 63;
  int c0 = lane & 15, qd = lane >> 4;
  __shared__ float Sred[576];
  for (int i = tid; i < 576; i += 256) Sred[i] = 0.f;
  __syncthreads();
  const bf16* qb = dwout + (((size_t)(b * 576 + h * 24)) << 14);
  const bf16* kb = dwout + (((size_t)(b * 576 + 192 + h * 24)) << 14);
  int r0 = c0;
  int r1 = (16 + c0 < 24) ? (16 + c0) : 23;
  f32x4 a00 = {0.f,0.f,0.f,0.f}, a01 = {0.f,0.f,0.f,0.f};
  f32x4 a10 = {0.f,0.f,0.f,0.f}, a11 = {0.f,0.f,0.f,0.f};
  int base = (((split << 2) + wave) << 9) + (qd << 3);
  for (int t = 0; t < 16; t++) {
    int kk = base + (t << 5);
    bf16x8 qa0 = *(const bf16x8*)(qb + (((size_t)r0) << 14) + kk);
    bf16x8 qa1 = *(const bf16x8*)(qb + (((size_t)r1) << 14) + kk);
    bf16x8 ka0 = *(const bf16x8*)(kb + (((size_t)r0) << 14) + kk);
    bf16x8 ka1 = *(const bf16x8*)(kb + (((size_t)r1) << 14) + kk);
    a00 = __builtin_amdgcn_mfma_f32_16x16x32_bf16(qa0, ka0, a00, 0, 0, 0);
    a01 = __builtin_amdgcn_mfma_f32_16x16x32_bf16(qa0, ka1, a01, 0, 0, 0);
    a10 = __builtin_amdgcn_mfma_f32_16x16x32_bf16(qa1, ka0, a10, 0, 0, 0);
    a11 = __builtin_amdgcn_mfma_f32_16x16x32_bf16(qa1, ka1, a11, 0, 0, 0);
  }
  f32x4 accs[4] = {a00, a01, a10, a11};
#pragma unroll
  for (int mi = 0; mi < 2; mi++)
#pragma unroll
    for (int nj = 0; nj < 2; nj++) {
      f32x4 a = accs[mi * 2 + nj];
#pragma unroll
      for (int r = 0; r < 4; r++) {
        int rrow = (mi << 4) + (qd << 2) + r;
        int cc = (nj << 4) + c0;
        if (rrow < 24 && cc < 24) atomicAdd(&Sred[rrow * 24 + cc], a[r]);
      }
    }
  __syncthreads();
  float* outp = Spart + (size_t)(bh * 8 + split) * 576;
  for (int i = tid; i < 576; i += 256) outp[i] = Sred[i];
}

// ------------------------------------------------- normalize + softmax(24x24)
__global__ __launch_bounds__(576) void attn_kernel(
    const float* __restrict__ Spart, const float* __restrict__ sumsq,
    float* __restrict__ attn) {
  int bh = blockIdx.x, tid = threadIdx.x;
  int b = bh >> 3, h = bh & 7;
  int c = tid / 24, d = tid % 24;
  float s = 0.f;
  for (int sp = 0; sp < 8; sp++) s += Spart[(size_t)(bh * 8 + sp) * 576 + tid];
  float nq = fmaxf(sqrtf(sumsq[b * 384 + h * 24 + c]), 1e-12f);
  float nk = fmaxf(sqrtf(sumsq[b * 384 + 192 + h * 24 + d]), 1e-12f);
  s = s / (nq * nk) * 0.20412414523193154f;
  __shared__ float Sm[576];
  Sm[tid] = s;
  __syncthreads();
  float mx = -1e30f;
  for (int j = 0; j < 24; j++) mx = fmaxf(mx, Sm[c * 24 + j]);
  float Z = 0.f;
  for (int j = 0; j < 24; j++) Z += __expf(Sm[c * 24 + j] - mx);
  attn[(size_t)bh * 576 + tid] = __expf(s - mx) / Z;
}

// ------------------------------------------------- attn x v + gating -> gated_t panels
__global__ __launch_bounds__(256) void av_kernel(
    const bf16* __restrict__ dwout, const float* __restrict__ attn,
    const float* __restrict__ gates2, bf16* __restrict__ gated_t) {
  int tid = threadIdx.x;
  int bh = blockIdx.y;
  int b = bh >> 3, h = bh & 7;
  int n = blockIdx.x * 256 + tid;
  __shared__ float At[576];
  for (int i = tid; i < 576; i += 256) At[i] = attn[(size_t)bh * 576 + i];
  __syncthreads();
  const bf16* vb = dwout + (((size_t)(b * 576 + 384 + h * 24)) << 14) + n;
  float acc[24];
#pragma unroll
  for (int c = 0; c < 24; c++) acc[c] = 0.f;
#pragma unroll
  for (int d0 = 0; d0 < 24; d0 += 4) {
    float v0 = (float)vb[(size_t)(d0 + 0) << 14];
    float v1 = (float)vb[(size_t)(d0 + 1) << 14];
    float v2 = (float)vb[(size_t)(d0 + 2) << 14];
    float v3 = (float)vb[(size_t)(d0 + 3) << 14];
#pragma unroll
    for (int c = 0; c < 24; c++) {
      const float4* ap = (const float4*)&At[c * 24 + d0];
      acc[c] += ap->x * v0 + ap->y * v1 + ap->z * v2 + ap->w * v3;
    }
  }
  float g = gates2[(((size_t)(b * 8 + h)) << 14) + n];
#pragma unroll
  for (int ch = 0; ch < 3; ch++) {
    bf16x8 o;
#pragma unroll
    for (int i = 0; i < 8; i++) o[i] = (bf16)(acc[ch * 8 + i] * g);
    int c = h * 24 + ch * 8;                       // aligned to 8
    int kc = c >> 5, j8 = (c >> 3) & 3;
    size_t dst = (((size_t)b * 6 + kc) << 19) + ((size_t)(n >> 4) << 9)
               + (((j8 << 4) + ((n & 15) ^ (j8 << 1))) << 3);
    *(bf16x8*)(gated_t + dst) = o;
  }
}

// ---------------------------------------------------------------- launch
extern "C" void kernel_launch(void* const* d_in, const int* in_sizes, int n_in,
                              void* d_out, int out_size, void* d_ws, size_t ws_size,
                              hipStream_t stream) {
  const void* x_raw    = d_in[0];
  const void* qkvw_raw = d_in[1];
  const void* dww_raw  = d_in[2];
  const void* projw_raw= d_in[3];
  const void* rtm_raw  = d_in[4];
  const void* rta_raw  = d_in[5];
  const int*  task     = (const int*)d_in[6];
  char* ws = (char*)d_ws;

  bf16*  qkv_raw = (bf16*)(ws);                    // 150,994,944 B
  bf16*  gated_t = qkv_raw;                        // reuse (dead after dwconv)
  bf16*  dwout   = (bf16*)(ws + 150994944);        // 150,994,944 B
  float* gates2  = (float*)(ws + 301989888);       // 4,194,304 B
  float* sumsq   = (float*)(ws + 306184192);       // 12,288 B
  float* Spart   = (float*)(ws + 306196480);       // 1,179,648 B
  float* attn    = (float*)(ws + 307376128);       // 147,456 B
  int*   flag    = (int*)(ws + 307523584);         // 128 B pad
  bf16*  xt      = (bf16*)(ws + 307523712);        // 50,331,648 B
  bf16*  qkv_wb  = (bf16*)(ws + 357855360);        // 221,184 B
  bf16*  dw_wb   = (bf16*)(ws + 358076544);        // 10,368 B
  bf16*  proj_wb = (bf16*)(ws + 358086912);        // 73,728 B

  hipMemsetAsync(sumsq, 0, 8 * 384 * sizeof(float), stream);
  detect_kernel<<<1, 256, 0, stream>>>((const u32*)x_raw, flag);
  wconvert_kernel<<<dim3(54, 3), 256, 0, stream>>>(qkvw_raw, qkv_wb, dww_raw, dw_wb,
                                                   projw_raw, proj_wb, flag);
  // transpose (panel layout) with fused router
  transpose_kernel<<<dim3(128, 8), 256, 0, stream>>>(x_raw, xt, flag,
                                                     rtm_raw, rta_raw, task, gates2);
  wgemm2_kernel<<<dim3(6, 64, 8), 256, 0, stream>>>(qkv_wb, xt, qkv_raw, 576, flag, 0);
  // 8x4 patch per thread, shfl edges
  dwconv_kernel<<<dim3(2, 576, 8), 256, 0, stream>>>(qkv_raw, dw_wb, dwout, sumsq);
  spart_kernel<<<dim3(8, 64), 256, 0, stream>>>(dwout, Spart);
  attn_kernel<<<64, 576, 0, stream>>>(Spart, sumsq, attn);
  av_kernel<<<dim3(64, 64), 256, 0, stream>>>(dwout, attn, gates2, gated_t);
  wgemm2_kernel<<<dim3(2, 64, 8), 256, 0, stream>>>(proj_wb, gated_t, d_out, 192, flag, 1);
}

// Round 11
// 394.640 us; speedup vs baseline: 1.1072x; 1.0447x over previous
//
#include <hip/hip_runtime.h>
#include <hip/hip_bf16.h>

typedef __bf16 bf16;
typedef __bf16 bf16x8 __attribute__((ext_vector_type(8)));
typedef __bf16 bf16x4 __attribute__((ext_vector_type(4)));
typedef float f32x4 __attribute__((ext_vector_type(4)));
typedef unsigned int u32;

#define NPIX 16384
#define CDIM 192

// Tiled-swizzled operand layout ("panel" layout), shared by xt, qkv_wb, proj_wb,
// gated_t:  element (row, k) of a [R][192] matrix lives at
//   panel(kc = k>>5) * R*32  +  (row>>4)*512  +  (slot)*8 + (k&7)
//   slot = j8*16 + ((row&15) ^ (j8<<1)),  j8 = (k>>3)&3
// This is exactly the LDS image the GEMM's slot8 fragment reads expect, so a
// linear gl2lds16 of 512-el groups reproduces the (0-conflict) LDS verbatim
// while every stage load is a contiguous, fully-coalesced 1KB.

// async 16B/lane global->LDS (lds base wave-uniform; HW adds lane*16 to LDS)
__device__ __forceinline__ void gl2lds16(const bf16* g, const bf16* l) {
  __builtin_amdgcn_global_load_lds(
      (const __attribute__((address_space(1))) u32*)(g),
      (__attribute__((address_space(3))) u32*)(l), 16, 0, 0);
}

// ------------------------------------------------- input dtype detector
__global__ __launch_bounds__(256) void detect_kernel(
    const u32* __restrict__ xw, int* __restrict__ flag) {
  int tid = threadIdx.x;
  int cnt = 0;
  for (int i = 0; i < 32; i++) {
    u32 w = xw[tid * 32 + i];
    u32 e = (w >> 7) & 0xFFu;   // exponent of low-half bf16
    if (e >= 0xC0u) cnt++;
  }
  for (int off = 32; off; off >>= 1) cnt += __shfl_down(cnt, off);
  __shared__ int red[4];
  if ((tid & 63) == 0) red[tid >> 6] = cnt;
  __syncthreads();
  if (tid == 0) *flag = (red[0] + red[1] + red[2] + red[3] >= 16) ? 1 : 0;
}

// ------------------------------------------------- weights -> bf16 (merged)
// qkv_w (M=576) and proj_w (M=192) are stored in panel layout; dw_w linear.
__global__ __launch_bounds__(256) void wconvert_kernel(
    const void* __restrict__ s0, bf16* __restrict__ d0,
    const void* __restrict__ s1, bf16* __restrict__ d1,
    const void* __restrict__ s2, bf16* __restrict__ d2,
    const int* __restrict__ flag) {
  int which = blockIdx.y;
  const void* src = which == 0 ? s0 : (which == 1 ? s1 : s2);
  bf16* dst = which == 0 ? d0 : (which == 1 ? d1 : d2);
  int n = which == 0 ? 110592 : (which == 1 ? 5184 : 36864);
  int base = (blockIdx.x * 256 + threadIdx.x) * 8;
  if (base >= n) return;
  bf16x8 o;
  if (*flag) {
    const float* s = (const float*)src;
    float4 lo = *(const float4*)(s + base);
    float4 hi = *(const float4*)(s + base + 4);
    o[0] = (bf16)lo.x; o[1] = (bf16)lo.y; o[2] = (bf16)lo.z; o[3] = (bf16)lo.w;
    o[4] = (bf16)hi.x; o[5] = (bf16)hi.y; o[6] = (bf16)hi.z; o[7] = (bf16)hi.w;
  } else {
    o = *(const bf16x8*)((const bf16*)src + base);
  }
  if (which != 1) {
    int M = (which == 0) ? 576 : 192;
    int m = base / 192, k = base - m * 192;          // k % 8 == 0
    int kc = k >> 5, j8 = (k >> 3) & 3;
    size_t dstoff = (size_t)kc * M * 32 + ((size_t)(m >> 4) << 9)
                  + (((j8 << 4) + ((m & 15) ^ (j8 << 1))) << 3);
    *(bf16x8*)(dst + dstoff) = o;
  } else {
    *(bf16x8*)(dst + base) = o;
  }
}

// ------------------------------------------------- x -> xt panels (+ fused router)
// Thread loads 8 c-rows x 4 n (coalesced); writes 4x 16B chunks in panel layout.
// Router fused: same x values dotted against W^T (LDS, broadcast reads) in f32,
// reduced shfl_xor(32) intra-wave then 4-way via LDS; identical top-2 gate math.
__global__ __launch_bounds__(256) void transpose_kernel(
    const void* __restrict__ xraw, bf16* __restrict__ xt,
    const int* __restrict__ flag, const void* __restrict__ wmain,
    const void* __restrict__ waux, const int* __restrict__ task,
    float* __restrict__ gates2) {
  __shared__ float wT[CDIM][8];      // 6 KB
  __shared__ float lred[4][128][8];  // 16 KB
  int t = threadIdx.x;
  int b = blockIdx.y;
  int n0 = blockIdx.x * 128;
  int f = *flag;
  const void* rw = (*task == 0) ? wmain : waux;
  for (int i = t; i < 8 * CDIM; i += 256) {
    int h = i / CDIM, c = i - h * CDIM;
    wT[c][h] = f ? ((const float*)rw)[i] : (float)((const bf16*)rw)[i];
  }
  __syncthreads();
  int nl = (t & 31) * 4;
  int cb = (t >> 5) * 8;             // 0..56
  float l[4][8];
#pragma unroll
  for (int j = 0; j < 4; j++)
#pragma unroll
    for (int h = 0; h < 8; h++) l[j][h] = 0.f;
  for (int ch = 0; ch < 3; ch++) {
    int c8 = ch * 64 + cb;
    float v[8][4];
    if (f) {
      const float* xp = (const float*)xraw + ((size_t)b * CDIM << 14) + n0 + nl;
#pragma unroll
      for (int i = 0; i < 8; i++) {
        float4 q = *(const float4*)(xp + ((size_t)(c8 + i) << 14));
        v[i][0] = q.x; v[i][1] = q.y; v[i][2] = q.z; v[i][3] = q.w;
      }
    } else {
      const bf16* xp = (const bf16*)xraw + ((size_t)b * CDIM << 14) + n0 + nl;
#pragma unroll
      for (int i = 0; i < 8; i++) {
        bf16x4 q = *(const bf16x4*)(xp + ((size_t)(c8 + i) << 14));
#pragma unroll
        for (int j = 0; j < 4; j++) v[i][j] = (float)q[j];
      }
    }
    // router partials
#pragma unroll
    for (int i = 0; i < 8; i++) {
      float4 wlo = *(const float4*)&wT[c8 + i][0];
      float4 whi = *(const float4*)&wT[c8 + i][4];
#pragma unroll
      for (int j = 0; j < 4; j++) {
        float xv = v[i][j];
        l[j][0] += xv * wlo.x; l[j][1] += xv * wlo.y;
        l[j][2] += xv * wlo.z; l[j][3] += xv * wlo.w;
        l[j][4] += xv * whi.x; l[j][5] += xv * whi.y;
        l[j][6] += xv * whi.z; l[j][7] += xv * whi.w;
      }
    }
    int kc = c8 >> 5, j8 = (c8 >> 3) & 3;
    size_t pb = (((size_t)b * 6 + kc) << 19);
#pragma unroll
    for (int j = 0; j < 4; j++) {
      bf16x8 o;
#pragma unroll
      for (int i = 0; i < 8; i++) o[i] = (bf16)v[i][j];
      int nn = n0 + nl + j;
      size_t dst = pb + ((size_t)(nn >> 4) << 9)
                 + (((j8 << 4) + ((nn & 15) ^ (j8 << 1))) << 3);
      *(bf16x8*)(xt + dst) = o;
    }
  }
  // ---- router reduce: g-bit0 is tid bit5 (intra-wave) -> shfl_xor 32
#pragma unroll
  for (int j = 0; j < 4; j++)
#pragma unroll
    for (int h = 0; h < 8; h++) l[j][h] += __shfl_xor(l[j][h], 32);
  int lane = t & 63, wid = t >> 6;
  if (lane < 32) {
#pragma unroll
    for (int j = 0; j < 4; j++) {
      *(float4*)&lred[wid][nl + j][0] = make_float4(l[j][0], l[j][1], l[j][2], l[j][3]);
      *(float4*)&lred[wid][nl + j][4] = make_float4(l[j][4], l[j][5], l[j][6], l[j][7]);
    }
  }
  __syncthreads();
  if (t < 128) {
    float lg[8];
#pragma unroll
    for (int h = 0; h < 8; h++)
      lg[h] = (lred[0][t][h] + lred[1][t][h]) + (lred[2][t][h] + lred[3][t][h]);
    int i1 = 0;
#pragma unroll
    for (int h = 1; h < 8; h++) if (lg[h] > lg[i1]) i1 = h;
    int i2 = (i1 == 0) ? 1 : 0;
#pragma unroll
    for (int h = 0; h < 8; h++) if (h != i1 && lg[h] > lg[i2]) i2 = h;
    float e = __expf(lg[i2] - lg[i1]);
    float g1 = 2.f / (1.f + e);
    float g2 = e * g1;
    float* gb = gates2 + (((size_t)b * 8) << 14) + n0 + t;
#pragma unroll
    for (int h = 0; h < 8; h++)
      gb[(size_t)h << 14] = (h == i1) ? g1 : ((h == i2) ? g2 : 0.f);
  }
}

// ------------------------------------------------- GEMM v9: ring + LDS-repacked epilogue
// C[z][m][n] = sum_k A[m][k] * Xt[z][n][k].  Block 96m x 256n, BK=32.
// Main loop: 3-buffer ring, counted vmcnt (round-9). Epilogue repacks the
// accumulator tile through LDS ([96][264] bf16 / 2x [48][260] f32, padded
// stride kills bank conflicts) and emits fully-coalesced 16B/lane stores
// (8 full 128B lines per wave-store) instead of 16-line 32B partial scatters
// -> 4x fewer L2 write requests, no partial-line merges, ~90 fewer VALU ops.
__global__ __launch_bounds__(256) void wgemm2_kernel(
    const bf16* __restrict__ A, const bf16* __restrict__ Xt,
    void* __restrict__ C, int M, const int* __restrict__ flag, int finalout) {
  __shared__ bf16 smem[33792];       // 67,584 B (3 buffers of 11264 el; epilogue scratch)
  int tid = threadIdx.x;
  int wave = tid >> 6, lane = tid & 63;
  int c0 = lane & 15, qd = lane >> 4;

  int nm = M / 96;                                   // 6 (qkv) or 2 (proj)
  int ord = blockIdx.x + nm * (blockIdx.y + (blockIdx.z << 6));
  int z = ord & 7;
  int local = ord >> 3;
  int mt = local % nm;
  int nt = local / nm;
  int m0 = mt * 96, n0 = nt << 8;

  const bf16* Xb = Xt + (size_t)z * CDIM * NPIX;
  size_t cbase = (size_t)z * M * NPIX;
  int Mx32 = M * 32;

  // frag-read slot: element offset of lane's 16B within a 16-row group
  int slot8 = ((qd << 4) + (c0 ^ (qd << 1))) << 3;

  f32x4 acc[6][4];
#pragma unroll
  for (int i = 0; i < 6; i++)
#pragma unroll
    for (int j = 0; j < 4; j++) acc[i][j] = {0.f, 0.f, 0.f, 0.f};

  auto STAGE = [&](int bufi, int kc) {
    int bb = bufi * 11264;
    const bf16* As = A + (size_t)kc * Mx32 + mt * 3072 + (lane << 3);
    const bf16* Bs = Xb + ((size_t)kc << 19)
                   + ((size_t)((nt << 4) + (wave << 2)) << 9) + (lane << 3);
    gl2lds16(As + (wave << 9), smem + bb + (wave << 9));
    if (wave < 2) gl2lds16(As + ((4 + wave) << 9), smem + bb + ((4 + wave) << 9));
    const bf16* bl = smem + bb + 3072 + (wave << 11);
    gl2lds16(Bs,        bl);
    gl2lds16(Bs +  512, bl + 512);
    gl2lds16(Bs + 1024, bl + 1024);
    gl2lds16(Bs + 1536, bl + 1536);
  };

  STAGE(0, 0);
  STAGE(1, 1);
#pragma unroll
  for (int t = 0; t < 6; t++) {
    if (t < 5) asm volatile("s_waitcnt vmcnt(5)" ::: "memory");
    else       asm volatile("s_waitcnt vmcnt(0)" ::: "memory");
    __builtin_amdgcn_sched_barrier(0);
    __builtin_amdgcn_s_barrier();
    __builtin_amdgcn_sched_barrier(0);
    if (t < 4) STAGE((t + 2) % 3, t + 2);            // overwrites buf read at t-1
    int bb = (t % 3) * 11264;
    bf16x8 af[6], bfr[4];
#pragma unroll
    for (int mi = 0; mi < 6; mi++)
      af[mi] = *(const bf16x8*)(smem + bb + mi * 512 + slot8);
#pragma unroll
    for (int nj = 0; nj < 4; nj++)
      bfr[nj] = *(const bf16x8*)(smem + bb + 3072 + (wave << 11) + nj * 512 + slot8);
#pragma unroll
    for (int mi = 0; mi < 6; mi++)
#pragma unroll
      for (int nj = 0; nj < 4; nj++)
        acc[mi][nj] = __builtin_amdgcn_mfma_f32_16x16x32_bf16(bfr[nj], af[mi], acc[mi][nj], 0, 0, 0);
  }

  // ---- epilogue: repack through LDS -> coalesced stores
  int f32o = finalout && (*flag);
  int ncol = (wave << 6) + (qd << 2);                // col within 256-wide tile
  __syncthreads();                                   // all waves done reading buf2
  if (!f32o) {
    bf16* lt = smem;                                 // [96][264] bf16 (50,688 B)
#pragma unroll
    for (int mi = 0; mi < 6; mi++) {
      int row = (mi << 4) + c0;
#pragma unroll
      for (int nj = 0; nj < 4; nj++) {
        bf16x4 o;
        o[0] = (bf16)acc[mi][nj][0]; o[1] = (bf16)acc[mi][nj][1];
        o[2] = (bf16)acc[mi][nj][2]; o[3] = (bf16)acc[mi][nj][3];
        *(bf16x4*)(lt + row * 264 + ncol + (nj << 4)) = o;
      }
    }
    __syncthreads();
    int rt0 = tid >> 5, cl = tid & 31;               // 8 rows / iter, 32 x 16B per row
#pragma unroll
    for (int it = 0; it < 12; it++) {
      int row = it * 8 + rt0;
      bf16x8 v = *(const bf16x8*)(lt + row * 264 + (cl << 3));
      *(bf16x8*)((bf16*)C + cbase + ((size_t)(m0 + row) << 14) + n0 + (cl << 3)) = v;
    }
  } else {
    float* lf = (float*)smem;                        // [48][260] f32 (49,920 B)
#pragma unroll
    for (int half = 0; half < 2; half++) {
      if (half) __syncthreads();
#pragma unroll
      for (int mi3 = 0; mi3 < 3; mi3++) {
        int row = (mi3 << 4) + c0;
        *(f32x4*)(lf + row * 260 + ncol)        = acc[half * 3 + mi3][0];
        *(f32x4*)(lf + row * 260 + ncol + 16)   = acc[half * 3 + mi3][1];
        *(f32x4*)(lf + row * 260 + ncol + 32)   = acc[half * 3 + mi3][2];
        *(f32x4*)(lf + row * 260 + ncol + 48)   = acc[half * 3 + mi3][3];
      }
      __syncthreads();
#pragma unroll
      for (int it = 0; it < 12; it++) {
        int row = it * 4 + wave;                     // 4 rows / iter, 64 x 16B per row
        f32x4 v = *(const f32x4*)(lf + row * 260 + (lane << 2));
        *(float4*)((float*)C + cbase + ((size_t)(m0 + half * 48 + row) << 14)
                   + n0 + (lane << 2)) = make_float4(v[0], v[1], v[2], v[3]);
      }
    }
  }
}

// ----------------------------------------------- depthwise 3x3 + q/k sumsq
// 8x4 patch per thread + SHFL EDGES: horizontal neighbors come from adjacent
// lanes' registers (lane l's vals[0] = lane l-1's vals[8]) instead of 12
// predicated scalar loads -> 7 VMEM insts/thread instead of 19. Cross-group
// shfl results land only at lx==0/15 where the image boundary forces 0.
__global__ __launch_bounds__(256) void dwconv_kernel(
    const bf16* __restrict__ qkv, const bf16* __restrict__ w9,
    bf16* __restrict__ out, float* __restrict__ sumsq) {
  int tid = threadIdx.x;
  int ch = blockIdx.y, b = blockIdx.z;
  int lx = tid & 15;
  int xs = lx << 3;                              // 0..120
  int y0 = (blockIdx.x << 6) + ((tid >> 4) << 2);  // 4-row group
  const bf16* in = qkv + (((size_t)(b * 576 + ch)) << 14);
  float wv[9];
#pragma unroll
  for (int i = 0; i < 9; i++) wv[i] = (float)w9[ch * 9 + i];
  float o[4][8];
#pragma unroll
  for (int r = 0; r < 4; r++)
#pragma unroll
    for (int i = 0; i < 8; i++) o[r][i] = 0.f;
#pragma unroll
  for (int rr = 0; rr < 6; rr++) {
    int yy = y0 - 1 + rr;
    if (yy < 0 || yy > 127) continue;            // zero padding rows (uniform per 16-lane group)
    const bf16* row = in + (yy << 7);
    bf16x8 v8 = *(const bf16x8*)(row + xs);
    float vals[10];
#pragma unroll
    for (int j = 0; j < 8; j++) vals[1 + j] = (float)v8[j];
    float lf = __shfl_up(vals[8], 1);            // lane l-1's px[xs-1]
    float rt = __shfl_down(vals[1], 1);          // lane l+1's px[xs+8]
    vals[0] = (lx > 0)  ? lf : 0.f;
    vals[9] = (lx < 15) ? rt : 0.f;
#pragma unroll
    for (int orow = 0; orow < 4; orow++) {
      int wrow = rr - orow;                      // compile-time under unroll
      if (wrow < 0 || wrow > 2) continue;
      float w0 = wv[wrow * 3 + 0], w1 = wv[wrow * 3 + 1], w2 = wv[wrow * 3 + 2];
#pragma unroll
      for (int i = 0; i < 8; i++)
        o[orow][i] += w0 * vals[i] + w1 * vals[i + 1] + w2 * vals[i + 2];
    }
  }
  float ss = 0.f;
  bf16* ob = out + (((size_t)(b * 576 + ch)) << 14);
#pragma unroll
  for (int r = 0; r < 4; r++) {
    bf16x8 ov;
#pragma unroll
    for (int i = 0; i < 8; i++) { ov[i] = (bf16)o[r][i]; ss += o[r][i] * o[r][i]; }
    *(bf16x8*)(ob + ((y0 + r) << 7) + xs) = ov;
  }
  if (ch < 384) {
#pragma unroll
    for (int off = 32; off; off >>= 1) ss += __shfl_down(ss, off);
    __shared__ float red[4];
    if ((tid & 63) == 0) red[tid >> 6] = ss;
    __syncthreads();
    if (tid == 0) atomicAdd(&sumsq[b * 384 + ch], red[0] + red[1] + red[2] + red[3]);
  }
}

// ------------------------------------------------- q k^T partials via MFMA
__global__ __launch_bounds__(256) void spart_kernel(
    const bf16* __restrict__ dwout, float* __restrict__ Spart) {
  int tid = threadIdx.x;
  int bh = blockIdx.y, split = blockIdx.x;
  int b = bh >> 3, h = bh & 7;
  int wave = tid >> 6, lane = tid & 63;
  int c0 = lane & 15, qd = lane >> 4;
  __shared__ float Sred[576];
  for (int i = tid; i < 576; i += 256) Sred[i] = 0.f;
  __syncthreads();
  const bf16* qb = dwout + (((size_t)(b * 576 + h * 24)) << 14);
  const bf16* kb = dwout + (((size_t)(b * 576 + 192 + h * 24)) << 14);
  int r0 = c0;
  int r1 = (16 + c0 < 24) ? (16 + c0) : 23;
  f32x4 a00 = {0.f,0.f,0.f,0.f}, a01 = {0.f,0.f,0.f,0.f};
  f32x4 a10 = {0.f,0.f,0.f,0.f}, a11 = {0.f,0.f,0.f,0.f};
  int base = (((split << 2) + wave) << 9) + (qd << 3);
  for (int t = 0; t < 16; t++) {
    int kk = base + (t << 5);
    bf16x8 qa0 = *(const bf16x8*)(qb + (((size_t)r0) << 14) + kk);
    bf16x8 qa1 = *(const bf16x8*)(qb + (((size_t)r1) << 14) + kk);
    bf16x8 ka0 = *(const bf16x8*)(kb + (((size_t)r0) << 14) + kk);
    bf16x8 ka1 = *(const bf16x8*)(kb + (((size_t)r1) << 14) + kk);
    a00 = __builtin_amdgcn_mfma_f32_16x16x32_bf16(qa0, ka0, a00, 0, 0, 0);
    a01 = __builtin_amdgcn_mfma_f32_16x16x32_bf16(qa0, ka1, a01, 0, 0, 0);
    a10 = __builtin_amdgcn_mfma_f32_16x16x32_bf16(qa1, ka0, a10, 0, 0, 0);
    a11 = __builtin_amdgcn_mfma_f32_16x16x32_bf16(qa1, ka1, a11, 0, 0, 0);
  }
  f32x4 accs[4] = {a00, a01, a10, a11};
#pragma unroll
  for (int mi = 0; mi < 2; mi++)
#pragma unroll
    for (int nj = 0; nj < 2; nj++) {
      f32x4 a = accs[mi * 2 + nj];
#pragma unroll
      for (int r = 0; r < 4; r++) {
        int rrow = (mi << 4) + (qd << 2) + r;
        int cc = (nj << 4) + c0;
        if (rrow < 24 && cc < 24) atomicAdd(&Sred[rrow * 24 + cc], a[r]);
      }
    }
  __syncthreads();
  float* outp = Spart + (size_t)(bh * 8 + split) * 576;
  for (int i = tid; i < 576; i += 256) outp[i] = Sred[i];
}

// ------------------------------------------------- normalize + softmax(24x24)
__global__ __launch_bounds__(576) void attn_kernel(
    const float* __restrict__ Spart, const float* __restrict__ sumsq,
    float* __restrict__ attn) {
  int bh = blockIdx.x, tid = threadIdx.x;
  int b = bh >> 3, h = bh & 7;
  int c = tid / 24, d = tid % 24;
  float s = 0.f;
  for (int sp = 0; sp < 8; sp++) s += Spart[(size_t)(bh * 8 + sp) * 576 + tid];
  float nq = fmaxf(sqrtf(sumsq[b * 384 + h * 24 + c]), 1e-12f);
  float nk = fmaxf(sqrtf(sumsq[b * 384 + 192 + h * 24 + d]), 1e-12f);
  s = s / (nq * nk) * 0.20412414523193154f;
  __shared__ float Sm[576];
  Sm[tid] = s;
  __syncthreads();
  float mx = -1e30f;
  for (int j = 0; j < 24; j++) mx = fmaxf(mx, Sm[c * 24 + j]);
  float Z = 0.f;
  for (int j = 0; j < 24; j++) Z += __expf(Sm[c * 24 + j] - mx);
  attn[(size_t)bh * 576 + tid] = __expf(s - mx) / Z;
}

// ------------------------------------------------- attn x v + gating -> gated_t panels
__global__ __launch_bounds__(256) void av_kernel(
    const bf16* __restrict__ dwout, const float* __restrict__ attn,
    const float* __restrict__ gates2, bf16* __restrict__ gated_t) {
  int tid = threadIdx.x;
  int bh = blockIdx.y;
  int b = bh >> 3, h = bh & 7;
  int n = blockIdx.x * 256 + tid;
  __shared__ float At[576];
  for (int i = tid; i < 576; i += 256) At[i] = attn[(size_t)bh * 576 + i];
  __syncthreads();
  const bf16* vb = dwout + (((size_t)(b * 576 + 384 + h * 24)) << 14) + n;
  float acc[24];
#pragma unroll
  for (int c = 0; c < 24; c++) acc[c] = 0.f;
#pragma unroll
  for (int d0 = 0; d0 < 24; d0 += 4) {
    float v0 = (float)vb[(size_t)(d0 + 0) << 14];
    float v1 = (float)vb[(size_t)(d0 + 1) << 14];
    float v2 = (float)vb[(size_t)(d0 + 2) << 14];
    float v3 = (float)vb[(size_t)(d0 + 3) << 14];
#pragma unroll
    for (int c = 0; c < 24; c++) {
      const float4* ap = (const float4*)&At[c * 24 + d0];
      acc[c] += ap->x * v0 + ap->y * v1 + ap->z * v2 + ap->w * v3;
    }
  }
  float g = gates2[(((size_t)(b * 8 + h)) << 14) + n];
#pragma unroll
  for (int ch = 0; ch < 3; ch++) {
    bf16x8 o;
#pragma unroll
    for (int i = 0; i < 8; i++) o[i] = (bf16)(acc[ch * 8 + i] * g);
    int c = h * 24 + ch * 8;                       // aligned to 8
    int kc = c >> 5, j8 = (c >> 3) & 3;
    size_t dst = (((size_t)b * 6 + kc) << 19) + ((size_t)(n >> 4) << 9)
               + (((j8 << 4) + ((n & 15) ^ (j8 << 1))) << 3);
    *(bf16x8*)(gated_t + dst) = o;
  }
}

// ---------------------------------------------------------------- launch
extern "C" void kernel_launch(void* const* d_in, const int* in_sizes, int n_in,
                              void* d_out, int out_size, void* d_ws, size_t ws_size,
                              hipStream_t stream) {
  const void* x_raw    = d_in[0];
  const void* qkvw_raw = d_in[1];
  const void* dww_raw  = d_in[2];
  const void* projw_raw= d_in[3];
  const void* rtm_raw  = d_in[4];
  const void* rta_raw  = d_in[5];
  const int*  task     = (const int*)d_in[6];
  char* ws = (char*)d_ws;

  bf16*  qkv_raw = (bf16*)(ws);                    // 150,994,944 B
  bf16*  gated_t = qkv_raw;                        // reuse (dead after dwconv)
  bf16*  dwout   = (bf16*)(ws + 150994944);        // 150,994,944 B
  float* gates2  = (float*)(ws + 301989888);       // 4,194,304 B
  float* sumsq   = (float*)(ws + 306184192);       // 12,288 B
  float* Spart   = (float*)(ws + 306196480);       // 1,179,648 B
  float* attn    = (float*)(ws + 307376128);       // 147,456 B
  int*   flag    = (int*)(ws + 307523584);         // 128 B pad
  bf16*  xt      = (bf16*)(ws + 307523712);        // 50,331,648 B
  bf16*  qkv_wb  = (bf16*)(ws + 357855360);        // 221,184 B
  bf16*  dw_wb   = (bf16*)(ws + 358076544);        // 10,368 B
  bf16*  proj_wb = (bf16*)(ws + 358086912);        // 73,728 B

  hipMemsetAsync(sumsq, 0, 8 * 384 * sizeof(float), stream);
  detect_kernel<<<1, 256, 0, stream>>>((const u32*)x_raw, flag);
  wconvert_kernel<<<dim3(54, 3), 256, 0, stream>>>(qkvw_raw, qkv_wb, dww_raw, dw_wb,
                                                   projw_raw, proj_wb, flag);
  // transpose (panel layout) with fused router
  transpose_kernel<<<dim3(128, 8), 256, 0, stream>>>(x_raw, xt, flag,
                                                     rtm_raw, rta_raw, task, gates2);
  wgemm2_kernel<<<dim3(6, 64, 8), 256, 0, stream>>>(qkv_wb, xt, qkv_raw, 576, flag, 0);
  // 8x4 patch per thread, shfl edges
  dwconv_kernel<<<dim3(2, 576, 8), 256, 0, stream>>>(qkv_raw, dw_wb, dwout, sumsq);
  spart_kernel<<<dim3(8, 64), 256, 0, stream>>>(dwout, Spart);
  attn_kernel<<<64, 576, 0, stream>>>(Spart, sumsq, attn);
  av_kernel<<<dim3(64, 64), 256, 0, stream>>>(dwout, attn, gates2, gated_t);
  wgemm2_kernel<<<dim3(2, 64, 8), 256, 0, stream>>>(proj_wb, gated_t, d_out, 192, flag, 1);
}